// Round 17
// baseline (519.072 us; speedup 1.0000x reference)
//
#include <hip/hip_runtime.h>
#include <cstdint>
#include <cstddef>

#define B_ 4
#define S_ 2048
#define D_ 1024
#define H_ 8
#define DH_ 128
#define MTOT 8192
#define NT_ 32
#define SCALE2 (0.08838834764831845f * 1.4426950408889634f)  // 1/sqrt(128) * log2(e)

typedef __attribute__((ext_vector_type(8))) short s16x8;
typedef __attribute__((ext_vector_type(4))) float f32x4;
typedef __attribute__((ext_vector_type(8))) __bf16 bf16x8;

static __device__ __forceinline__ f32x4 mfma16(s16x8 a, s16x8 b, f32x4 c) {
  return __builtin_amdgcn_mfma_f32_16x16x32_bf16(
      __builtin_bit_cast(bf16x8, a), __builtin_bit_cast(bf16x8, b), c, 0, 0, 0);
}
static __device__ __forceinline__ unsigned short f2bf(float f) {
  unsigned u = __builtin_bit_cast(unsigned, f);
  u += 0x7fffu + ((u >> 16) & 1u);
  return (unsigned short)(u >> 16);
}
static __device__ __forceinline__ float bf2f(unsigned short u) {
  return __builtin_bit_cast(float, (unsigned)u << 16);
}
// packed f32x2 -> bf16x2 (lo = a, hi = b)
static __device__ __forceinline__ unsigned cvtpk2(float a, float b) {
  unsigned r;
  asm("v_cvt_pk_bf16_f32 %0, %1, %2" : "=v"(r) : "v"(a), "v"(b));
  return r;
}
// async global->LDS, 16B per lane; LDS dest = wave-uniform base + lane*16
static __device__ __forceinline__ void gload_lds16(const void* g, void* l) {
  __builtin_amdgcn_global_load_lds(
      (__attribute__((address_space(1))) void*)(void*)(g),
      (__attribute__((address_space(3))) void*)(l), 16, 0, 0);
}

// ---------------- x f32 -> bf16 AND wo f32 -> bf16, one launch ----------------
__global__ __launch_bounds__(256) void xconv2_kernel(const float* __restrict__ x,
                                                     unsigned short* __restrict__ xb,
                                                     const float* __restrict__ wo,
                                                     unsigned short* __restrict__ wob) {
  if (blockIdx.x < 8192) {
    long i = ((long)blockIdx.x * 256 + threadIdx.x) * 4;
    float4 v = *(const float4*)(x + i);
    ushort4 o;
    o.x = f2bf(v.x); o.y = f2bf(v.y); o.z = f2bf(v.z); o.w = f2bf(v.w);
    *(ushort4*)(xb + i) = o;
  } else {
    long i = ((long)(blockIdx.x - 8192) * 256 + threadIdx.x) * 4;
    float4 v = *(const float4*)(wo + i);
    ushort4 o;
    o.x = f2bf(v.x); o.y = f2bf(v.y); o.z = f2bf(v.z); o.w = f2bf(v.w);
    *(ushort4*)(wob + i) = o;
  }
}

// ---------------- routing, wave-aggregated (1 atomic per wave per category) ---
__global__ __launch_bounds__(256) void route_kernel(const int* __restrict__ levels,
                                                    int* __restrict__ cnt,
                                                    int* __restrict__ ridx,
                                                    int* __restrict__ act,
                                                    int* __restrict__ act2) {
  const int row = blockIdx.x * 256 + threadIdx.x;
  const int lane = threadIdx.x & 63;
  const int lvl = levels[row];
  const unsigned long long lmlt = (lane == 63) ? ~0ULL >> 1 : (1ULL << lane) - 1;

#pragma unroll
  for (int c = 0; c < 2; c++) {
    bool pred = (lvl == c);
    unsigned long long mask = __ballot(pred);
    int total = __popcll(mask);
    if (total) {
      int leader = __ffsll((long long)mask) - 1;
      int base = 0;
      if (lane == leader) base = atomicAdd(&cnt[c], total);
      base = __shfl(base, leader);
      if (pred) ridx[c * MTOT + base + __popcll(mask & lmlt)] = row;
    }
  }
  {
    bool pred = (lvl < 2);
    unsigned long long mask = __ballot(pred);
    int total = __popcll(mask);
    if (total) {
      int leader = __ffsll((long long)mask) - 1;
      int base = 0;
      if (lane == leader) base = atomicAdd(&cnt[2], total);
      base = __shfl(base, leader);
      if (pred) act[base + __popcll(mask & lmlt)] = row;
    }
    unsigned long long mask2 = ~mask;
    int total2 = 64 - total;
    if (total2) {
      int leader2 = __ffsll((long long)mask2) - 1;
      int base2 = 0;
      if (lane == leader2) base2 = atomicAdd(&cnt[3], total2);
      base2 = __shfl(base2, leader2);
      if (!pred) act2[base2 + __popcll(mask2 & lmlt)] = row;
    }
  }
}

// ---------------- level>=2 rows: q/k/v = bias, hsel half of z = 0 -------------
__global__ __launch_bounds__(256) void lvl2fill_kernel(
    const int* __restrict__ act2, const int* __restrict__ cntp,
    const float* __restrict__ bq, const float* __restrict__ bk,
    const float* __restrict__ bv,
    unsigned short* __restrict__ qb, unsigned short* __restrict__ kb,
    unsigned short* __restrict__ vb, unsigned short* __restrict__ z) {
  const int idx = blockIdx.x;
  if (idx >= *cntp) return;
  const long row = act2[idx];
  const int t = threadIdx.x;
  const float4 q4 = *(const float4*)(bq + t * 4);
  const float4 k4 = *(const float4*)(bk + t * 4);
  const float4 v4 = *(const float4*)(bv + t * 4);
  ushort4 qo, ko, vo;
  qo.x = f2bf(q4.x * SCALE2); qo.y = f2bf(q4.y * SCALE2);
  qo.z = f2bf(q4.z * SCALE2); qo.w = f2bf(q4.w * SCALE2);
  ko.x = f2bf(k4.x); ko.y = f2bf(k4.y); ko.z = f2bf(k4.z); ko.w = f2bf(k4.w);
  vo.x = f2bf(v4.x); vo.y = f2bf(v4.y); vo.z = f2bf(v4.z); vo.w = f2bf(v4.w);
  *(ushort4*)(qb + row * 1024 + t * 4) = qo;
  *(ushort4*)(kb + row * 1024 + t * 4) = ko;
  *(ushort4*)(vb + row * 1024 + t * 4) = vo;
  *(ushort4*)(z + row * 2048 + t * 4) = (ushort4){0, 0, 0, 0};
}

// ---------------- all weight transposes in one launch ----------------
struct WtDesc { const float* src; unsigned short* dst; long dst_ld; long dst_off; };
struct WtArgs { WtDesc d[10]; };
__global__ __launch_bounds__(256) void wtrans_all_kernel(WtArgs a) {
  __shared__ unsigned short tile[32][33];
  const int wi = blockIdx.y >> 5;
  const WtDesc de = a.d[wi];
  int r0 = (blockIdx.y & 31) * 32, c0 = blockIdx.x * 32;
  int tr = threadIdx.x >> 5, tc = threadIdx.x & 31;
#pragma unroll
  for (int i = 0; i < 4; i++)
    tile[tr + i * 8][tc] = f2bf(de.src[(long)(r0 + tr + i * 8) * 1024 + c0 + tc]);
  __syncthreads();
#pragma unroll
  for (int i = 0; i < 4; i++)
    de.dst[(long)(c0 + tr + i * 8) * de.dst_ld + de.dst_off + r0 + tc] = tile[tc][tr + i * 8];
}

// ---------------- v bf16 [B,S,H,DH] -> [B,H,DH,S'] with key-slot permutation --
__global__ __launch_bounds__(256) void vtrans_kernel(const unsigned short* __restrict__ V,
                                                     unsigned short* __restrict__ Vt) {
  __shared__ unsigned short tile[32][33];
  int b = blockIdx.z;
  int h = blockIdx.y >> 2, d0 = (blockIdx.y & 3) * 32;
  int s0 = blockIdx.x * 32;
  int tr = threadIdx.x >> 5, tc = threadIdx.x & 31;
#pragma unroll
  for (int i = 0; i < 4; i++)
    tile[tr + i * 8][tc] = V[((long)(b * S_) + s0 + tr + i * 8) * D_ + h * DH_ + d0 + tc];
  __syncthreads();
  const int sk = s0 + tc;
  const int k6 = sk & 63;
  const int slot = ((k6 >> 5) << 5) | (((k6 >> 2) & 3) << 3) | (((k6 >> 4) & 1) << 2) | (k6 & 3);
  const int ss = (sk & ~63) | slot;
#pragma unroll
  for (int i = 0; i < 4; i++)
    Vt[((long)(b * H_ + h) * DH_ + d0 + tr + i * 8) * S_ + ss] = tile[tc][tr + i * 8];
}

// ---------------- 8-wave GEMM: 128^2 tile, 512 thr ----------------
template <int TAG>
__global__ __launch_bounds__(512) void gemm8_kernel(
    const unsigned short* __restrict__ A, int lda,
    const unsigned short* __restrict__ Wt, int ldw,
    const float* __restrict__ bias, float oscale,
    unsigned short* __restrict__ Cb, int ldc,
    int K, int do_silu) {
  __shared__ unsigned short lA[128 * 64];
  __shared__ unsigned short lB[128 * 64];
  const int t = threadIdx.x;
  const int wid = t >> 6, lane = t & 63;
  const int g = lane >> 4, lc = lane & 15;
  const int wr = wid >> 1, wc = wid & 1;   // 4x2 wave grid: 32-row x 64-col subtiles
  const int nwg = gridDim.x * gridDim.y;
  int flat = blockIdx.x + gridDim.x * blockIdx.y;
  flat = (flat & 7) * (nwg >> 3) + (flat >> 3);
  const int m0 = (flat / gridDim.x) * 128;
  const int n0 = (flat % gridDim.x) * 128;
  const int srow = lane >> 3, scol = lane & 7;
  const int sxor = (scol ^ srow) << 4;

  f32x4 acc[2][4];
#pragma unroll
  for (int i = 0; i < 2; i++)
#pragma unroll
    for (int j = 0; j < 4; j++) acc[i][j] = (f32x4){0.f, 0.f, 0.f, 0.f};

  const int nk = K >> 6;
  for (int kt = 0; kt < nk; ++kt) {
    const int k0 = kt << 6;
#pragma unroll
    for (int i = 0; i < 2; i++) {
      const int r0 = wid * 16 + i * 8;
      gload_lds16((const char*)(A + (m0 + r0 + srow) * (long)lda + k0) + sxor,
                  (char*)lA + r0 * 128);
      gload_lds16((const char*)(Wt + (n0 + r0 + srow) * (long)ldw + k0) + sxor,
                  (char*)lB + r0 * 128);
    }
    __syncthreads();
#pragma unroll
    for (int kk = 0; kk < 2; kk++) {
      s16x8 af[2], bfr[4];
#pragma unroll
      for (int i = 0; i < 2; i++) {
        int row = wr * 32 + i * 16 + lc;
        af[i] = *(const s16x8*)((const char*)lA + row * 128 +
                                ((kk * 64 + g * 16) ^ ((row & 7) << 4)));
      }
#pragma unroll
      for (int j = 0; j < 4; j++) {
        int row = wc * 64 + j * 16 + lc;
        bfr[j] = *(const s16x8*)((const char*)lB + row * 128 +
                                 ((kk * 64 + g * 16) ^ ((row & 7) << 4)));
      }
#pragma unroll
      for (int i = 0; i < 2; i++)
#pragma unroll
        for (int j = 0; j < 4; j++) acc[i][j] = mfma16(af[i], bfr[j], acc[i][j]);
    }
    __syncthreads();
  }
#pragma unroll
  for (int i = 0; i < 2; i++) {
    const long rbase = m0 + wr * 32 + i * 16 + g * 4;
#pragma unroll
    for (int j = 0; j < 4; j++) {
      const int col = n0 + wc * 64 + j * 16 + lc;
      const float bv = bias[col];
#pragma unroll
      for (int r = 0; r < 4; r++) {
        float v = (acc[i][j][r] + bv) * oscale;
        if (do_silu) v = v / (1.f + __expf(-v));
        Cb[(rbase + r) * (long)ldc + col] = f2bf(v);
      }
    }
  }
}

// ---------------- 8-wave merged MoE GEMM ----------------
template <int RMAP>
__global__ __launch_bounds__(512) void gemm8_moe_kernel(
    const unsigned short* __restrict__ A, int lda,
    const unsigned short* __restrict__ Wt0, int ldw,
    const float* __restrict__ bias0,
    unsigned short* __restrict__ Cb, int ldc,
    int K, int do_silu, const int* __restrict__ ridx, const int* __restrict__ cnt2) {
  __shared__ unsigned short lA[128 * 64];
  __shared__ unsigned short lB[128 * 64];
  const int t = threadIdx.x;
  const int wid = t >> 6, lane = t & 63;
  const int g = lane >> 4, lc = lane & 15;
  const int wr = wid >> 1, wc = wid & 1;
  const int nwg = gridDim.x * gridDim.y;
  int flat = blockIdx.x + gridDim.x * blockIdx.y;
  flat = (flat & 7) * (nwg >> 3) + (flat >> 3);
  const int m0 = (flat / gridDim.x) * 128;
  const int n0 = (flat % gridDim.x) * 128;
  const int lvl = m0 >> 12;
  const int lm0 = m0 & 4095;
  if (lm0 >= cnt2[lvl]) return;
  const unsigned short* Wt = Wt0 + (long)lvl * 1048576;
  const float* bias = bias0 + lvl * 1024;
  const int srow = lane >> 3, scol = lane & 7;
  const int sxor = (scol ^ srow) << 4;

  const unsigned short* abase[2];
#pragma unroll
  for (int i = 0; i < 2; i++) {
    int ar;
    if (RMAP) ar = ridx[lvl * MTOT + lm0 + wid * 16 + i * 8 + srow];
    else ar = m0 + wid * 16 + i * 8 + srow;
    abase[i] = A + (long)ar * lda;
  }

  f32x4 acc[2][4];
#pragma unroll
  for (int i = 0; i < 2; i++)
#pragma unroll
    for (int j = 0; j < 4; j++) acc[i][j] = (f32x4){0.f, 0.f, 0.f, 0.f};

  const int nk = K >> 6;
  for (int kt = 0; kt < nk; ++kt) {
    const int k0 = kt << 6;
#pragma unroll
    for (int i = 0; i < 2; i++) {
      const int r0 = wid * 16 + i * 8;
      gload_lds16((const char*)(abase[i] + k0) + sxor, (char*)lA + r0 * 128);
      gload_lds16((const char*)(Wt + (n0 + r0 + srow) * (long)ldw + k0) + sxor,
                  (char*)lB + r0 * 128);
    }
    __syncthreads();
#pragma unroll
    for (int kk = 0; kk < 2; kk++) {
      s16x8 af[2], bfr[4];
#pragma unroll
      for (int i = 0; i < 2; i++) {
        int row = wr * 32 + i * 16 + lc;
        af[i] = *(const s16x8*)((const char*)lA + row * 128 +
                                ((kk * 64 + g * 16) ^ ((row & 7) << 4)));
      }
#pragma unroll
      for (int j = 0; j < 4; j++) {
        int row = wc * 64 + j * 16 + lc;
        bfr[j] = *(const s16x8*)((const char*)lB + row * 128 +
                                 ((kk * 64 + g * 16) ^ ((row & 7) << 4)));
      }
#pragma unroll
      for (int i = 0; i < 2; i++)
#pragma unroll
        for (int j = 0; j < 4; j++) acc[i][j] = mfma16(af[i], bfr[j], acc[i][j]);
    }
    __syncthreads();
  }
#pragma unroll
  for (int i = 0; i < 2; i++) {
    const long rbase = m0 + wr * 32 + i * 16 + g * 4;
#pragma unroll
    for (int j = 0; j < 4; j++) {
      const int col = n0 + wc * 64 + j * 16 + lc;
      const float bv = bias[col];
#pragma unroll
      for (int r = 0; r < 4; r++) {
        float v = acc[i][j][r] + bv;
        if (do_silu) v = v / (1.f + __expf(-v));
        Cb[(rbase + r) * (long)ldc + col] = f2bf(v);
      }
    }
  }
}

// ---------------- Wct partial GEMM ----------------
__global__ __launch_bounds__(256) void wct_gemm_kernel(
    const unsigned short* __restrict__ A,   // i1t+1024, lda 2048
    const unsigned short* __restrict__ Wb,  // wob, ldw 1024
    float* __restrict__ Cf) {               // [4][1024][1024]
  __shared__ unsigned short lA[128 * 64];
  __shared__ unsigned short lB[128 * 64];
  const int t = threadIdx.x;
  const int wid = t >> 6, lane = t & 63;
  const int g = lane >> 4, lc = lane & 15;
  const int wr = wid >> 1, wc = wid & 1;
  const int chunk = blockIdx.y >> 3;
  const int m0 = (blockIdx.y & 7) * 128;
  const int n0 = blockIdx.x * 128;
  const unsigned short* A0 = A + chunk * 256;
  const unsigned short* W0 = Wb + chunk * 256;
  float* C0 = Cf + (long)chunk * 1048576;
  const int srow = lane >> 3, scol = lane & 7;
  const int sxor = (scol ^ srow) << 4;

  f32x4 acc[4][4];
#pragma unroll
  for (int i = 0; i < 4; i++)
#pragma unroll
    for (int j = 0; j < 4; j++) acc[i][j] = (f32x4){0.f, 0.f, 0.f, 0.f};

  for (int kt = 0; kt < 4; ++kt) {
    const int k0 = kt << 6;
#pragma unroll
    for (int i = 0; i < 4; i++) {
      const int r0 = wid * 32 + i * 8;
      gload_lds16((const char*)(A0 + (m0 + r0 + srow) * 2048L + k0) + sxor,
                  (char*)lA + r0 * 128);
      gload_lds16((const char*)(W0 + (n0 + r0 + srow) * 1024L + k0) + sxor,
                  (char*)lB + r0 * 128);
    }
    __syncthreads();
#pragma unroll
    for (int kk = 0; kk < 2; kk++) {
      s16x8 af[4], bfr[4];
#pragma unroll
      for (int i = 0; i < 4; i++) {
        int row = wr * 64 + i * 16 + lc;
        af[i] = *(const s16x8*)((const char*)lA + row * 128 +
                                ((kk * 64 + g * 16) ^ ((row & 7) << 4)));
      }
#pragma unroll
      for (int j = 0; j < 4; j++) {
        int row = wc * 64 + j * 16 + lc;
        bfr[j] = *(const s16x8*)((const char*)lB + row * 128 +
                                 ((kk * 64 + g * 16) ^ ((row & 7) << 4)));
      }
#pragma unroll
      for (int i = 0; i < 4; i++)
#pragma unroll
        for (int j = 0; j < 4; j++) acc[i][j] = mfma16(af[i], bfr[j], acc[i][j]);
    }
    __syncthreads();
  }
#pragma unroll
  for (int i = 0; i < 4; i++) {
    const long rbase = m0 + wr * 64 + i * 16 + g * 4;
#pragma unroll
    for (int j = 0; j < 4; j++) {
      const int col = n0 + wc * 64 + j * 16 + lc;
#pragma unroll
      for (int r = 0; r < 4; r++) C0[(rbase + r) * 1024L + col] = acc[i][j][r];
    }
  }
}

// ---------------- wct reduce: sum 4 K-chunks -> bf16 into i1t cols [1024:2048)
__global__ __launch_bounds__(256) void wct_reduce_kernel(
    const float* __restrict__ hraw, unsigned short* __restrict__ i1t) {
  long e = ((long)blockIdx.x * 256 + threadIdx.x) * 2;
  float a0 = hraw[e] + hraw[e + 1048576] + hraw[e + 2097152] + hraw[e + 3145728];
  float a1 = hraw[e + 1] + hraw[e + 1 + 1048576] + hraw[e + 1 + 2097152] +
             hraw[e + 1 + 3145728];
  unsigned pk = cvtpk2(a0, a1);
  long n = e >> 10, c = e & 1023;
  *(unsigned*)(i1t + n * 2048 + 1024 + c) = pk;
}

// ---------------- bias_c[n] = i1b[n] + sum_a bo[a] * W2t[n,a] (parallel) ------
__global__ __launch_bounds__(256) void biascomb_kernel(
    const unsigned short* __restrict__ i1t, const float* __restrict__ bo,
    const float* __restrict__ i1b, float* __restrict__ bias_c) {
  const int n = blockIdx.x, t = threadIdx.x;
  ushort4 w = *(const ushort4*)(i1t + (long)n * 2048 + 1024 + t * 4);
  float4 b = *(const float4*)(bo + t * 4);
  float s = bf2f(w.x) * b.x + bf2f(w.y) * b.y + bf2f(w.z) * b.z + bf2f(w.w) * b.w;
#pragma unroll
  for (int m = 32; m; m >>= 1) s += __shfl_xor(s, m);
  __shared__ float ws_[4];
  if ((t & 63) == 0) ws_[t >> 6] = s;
  __syncthreads();
  if (t == 0) bias_c[n] = i1b[n] + ws_[0] + ws_[1] + ws_[2] + ws_[3];
}

// ---------------- LayerNorm merged MoE (bf16 in): compact -> scatter ----------
__global__ __launch_bounds__(256) void ln_moe_kernel(
    const unsigned short* __restrict__ in, const int* __restrict__ ridx,
    const int* __restrict__ cnt2,
    const float* __restrict__ gg0, const float* __restrict__ bb0,
    unsigned short* __restrict__ outb, long ldo) {
  const int row = blockIdx.x;
  const int lvl = row >> 12;
  const int lrow = row & 4095;
  if (lrow >= cnt2[lvl]) return;
  const int orow = ridx[lvl * MTOT + lrow];
  const float* gg = gg0 + lvl * 1024;
  const float* bb = bb0 + lvl * 1024;
  const int t = threadIdx.x;
  const ushort4 u = *(const ushort4*)(in + (long)row * D_ + t * 4);
  float v0 = bf2f(u.x), v1 = bf2f(u.y), v2 = bf2f(u.z), v3 = bf2f(u.w);
  float s1 = v0 + v1 + v2 + v3;
  float s2 = v0 * v0 + v1 * v1 + v2 * v2 + v3 * v3;
#pragma unroll
  for (int m = 32; m; m >>= 1) {
    s1 += __shfl_xor(s1, m);
    s2 += __shfl_xor(s2, m);
  }
  __shared__ float w1[4], w2[4];
  if ((t & 63) == 0) { w1[t >> 6] = s1; w2[t >> 6] = s2; }
  __syncthreads();
  s1 = w1[0] + w1[1] + w1[2] + w1[3];
  s2 = w2[0] + w2[1] + w2[2] + w2[3];
  const float mu = s1 * (1.f / D_);
  const float var = s2 * (1.f / D_) - mu * mu;
  const float rs = rsqrtf(var + 1e-5f);
  float vv[4] = {v0, v1, v2, v3};
#pragma unroll
  for (int jj = 0; jj < 4; jj++) {
    int col = t * 4 + jj;
    float y = (vv[jj] - mu) * rs * gg[col] + bb[col];
    outb[(long)orow * ldo + col] = f2bf(y);
  }
}

// ---------------- final LayerNorm (bf16 in, f32 out) ----------------
__global__ __launch_bounds__(256) void ln_kernel(
    const unsigned short* __restrict__ in,
    const float* __restrict__ gg, const float* __restrict__ bb,
    float* __restrict__ outf) {
  const int row = blockIdx.x;
  const int t = threadIdx.x;
  const ushort4 u = *(const ushort4*)(in + (long)row * D_ + t * 4);
  float v0 = bf2f(u.x), v1 = bf2f(u.y), v2 = bf2f(u.z), v3 = bf2f(u.w);
  float s1 = v0 + v1 + v2 + v3;
  float s2 = v0 * v0 + v1 * v1 + v2 * v2 + v3 * v3;
#pragma unroll
  for (int m = 32; m; m >>= 1) {
    s1 += __shfl_xor(s1, m);
    s2 += __shfl_xor(s2, m);
  }
  __shared__ float w1[4], w2[4];
  if ((t & 63) == 0) { w1[t >> 6] = s1; w2[t >> 6] = s2; }
  __syncthreads();
  s1 = w1[0] + w1[1] + w1[2] + w1[3];
  s2 = w2[0] + w2[1] + w2[2] + w2[3];
  const float mu = s1 * (1.f / D_);
  const float var = s2 * (1.f / D_) - mu * mu;
  const float rs = rsqrtf(var + 1e-5f);
  float vv[4] = {v0, v1, v2, v3};
#pragma unroll
  for (int jj = 0; jj < 4; jj++) {
    int col = t * 4 + jj;
    outf[(long)row * D_ + col] = (vv[jj] - mu) * rs * gg[col] + bb[col];
  }
}

// ---------------- fused QKV GEMM, routed over active rows --------------------
__global__ __launch_bounds__(256) void gemm_qkv_kernel(
    const unsigned short* __restrict__ A, int lda,
    const unsigned short* __restrict__ Wt,
    const float* __restrict__ bq, const float* __restrict__ bk,
    const float* __restrict__ bv,
    unsigned short* __restrict__ qb, unsigned short* __restrict__ kb,
    unsigned short* __restrict__ vb,
    const int* __restrict__ act, const int* __restrict__ cntp) {
  __shared__ unsigned short lA[128 * 64];
  __shared__ unsigned short lB[128 * 64];
  const int t = threadIdx.x;
  const int wid = t >> 6, lane = t & 63;
  const int g = lane >> 4, lc = lane & 15;
  const int wr = wid >> 1, wc = wid & 1;
  const int nwg = gridDim.x * gridDim.y;
  int flat = blockIdx.x + gridDim.x * blockIdx.y;
  flat = (flat & 7) * (nwg >> 3) + (flat >> 3);
  const int m0 = (flat / gridDim.x) * 128;
  const int n0 = (flat % gridDim.x) * 128;
  if (m0 >= *cntp) return;
  const int srow = lane >> 3, scol = lane & 7;
  const int sxor = (scol ^ srow) << 4;

  const unsigned short* abase[4];
#pragma unroll
  for (int i = 0; i < 4; i++)
    abase[i] = A + (long)act[m0 + wid * 32 + i * 8 + srow] * lda;

  f32x4 acc[4][4];
#pragma unroll
  for (int i = 0; i < 4; i++)
#pragma unroll
    for (int j = 0; j < 4; j++) acc[i][j] = (f32x4){0.f, 0.f, 0.f, 0.f};

  for (int kt = 0; kt < 16; ++kt) {
    const int k0 = kt << 6;
#pragma unroll
    for (int i = 0; i < 4; i++) {
      const int r0 = wid * 32 + i * 8;
      gload_lds16((const char*)(abase[i] + k0) + sxor, (char*)lA + r0 * 128);
      gload_lds16((const char*)(Wt + (n0 + r0 + srow) * 1024 + k0) + sxor,
                  (char*)lB + r0 * 128);
    }
    __syncthreads();
#pragma unroll
    for (int kk = 0; kk < 2; kk++) {
      s16x8 af[4], bfr[4];
#pragma unroll
      for (int i = 0; i < 4; i++) {
        int row = wr * 64 + i * 16 + lc;
        af[i] = *(const s16x8*)((const char*)lA + row * 128 +
                                ((kk * 64 + g * 16) ^ ((row & 7) << 4)));
      }
#pragma unroll
      for (int j = 0; j < 4; j++) {
        int row = wc * 64 + j * 16 + lc;
        bfr[j] = *(const s16x8*)((const char*)lB + row * 128 +
                                 ((kk * 64 + g * 16) ^ ((row & 7) << 4)));
      }
#pragma unroll
      for (int i = 0; i < 4; i++)
#pragma unroll
        for (int j = 0; j < 4; j++) acc[i][j] = mfma16(af[i], bfr[j], acc[i][j]);
    }
    __syncthreads();
  }
  const int whichB = n0 >> 10;  // block-uniform: 0=q, 1=k, 2=v
  const float* bias = whichB == 0 ? bq : whichB == 1 ? bk : bv;
  unsigned short* Cb = whichB == 0 ? qb : whichB == 1 ? kb : vb;
  const float oscale = whichB == 0 ? (float)SCALE2 : 1.0f;
  const int nb = n0 & 1023;
#pragma unroll
  for (int i = 0; i < 4; i++) {
    const int ribase = m0 + wr * 64 + i * 16 + g * 4;
#pragma unroll
    for (int j = 0; j < 4; j++) {
      const int col = nb + wc * 64 + j * 16 + lc;
      const float bvv = bias[col];
#pragma unroll
      for (int r = 0; r < 4; r++) {
        float v = (acc[i][j][r] + bvv) * oscale;
        Cb[(long)act[ribase + r] * 1024L + col] = f2bf(v);
      }
    }
  }
}

// ---------------- flash attention, swapped QK^T, 2-tile pipelined PV ----------
__global__ __launch_bounds__(256, 2) void flash_kernel(
    const unsigned short* __restrict__ Q, const unsigned short* __restrict__ Kb,
    const unsigned short* __restrict__ Vt,
    unsigned short* __restrict__ zatt, float* __restrict__ Mo, float* __restrict__ Lo) {
  __shared__ unsigned short lK[2][64 * 128];   // [key][dh], 256B rows (32KB)
  __shared__ unsigned short lV[3][128 * 64];   // [dh][key-slot], 128B rows (48KB)
  const int t = threadIdx.x, wid = t >> 6, lane = t & 63;
  const int g = lane >> 4, lc = lane & 15;
  const int d = blockIdx.x + 16 * (blockIdx.y + 8 * blockIdx.z);
  const int qd = d >> 3, rd = d & 7;
  const int grp = rd + 8 * (qd >> 4);
  const int b = grp >> 3, h = grp & 7, q0 = (qd & 15) * 128;
  const int k_l4 = lane >> 4, k_c = lane & 15;  // K stage: 4 rows/instr
  const int v_l3 = lane >> 3, v_c = lane & 7;   // V stage: 8 rows/instr

  s16x8 qf[2][4];
#pragma unroll
  for (int qi = 0; qi < 2; qi++)
#pragma unroll
    for (int kk = 0; kk < 4; kk++)
      qf[qi][kk] = *(const s16x8*)(Q +
          ((long)(b * S_ + q0 + wid * 32 + qi * 16 + lc)) * D_ + h * DH_ + kk * 32 + g * 8);

  f32x4 acco[2][8];
#pragma unroll
  for (int qi = 0; qi < 2; qi++)
#pragma unroll
    for (int dn = 0; dn < 8; dn++) acco[qi][dn] = (f32x4){0.f, 0.f, 0.f, 0.f};
  float m_run[2] = {-1e30f, -1e30f}, l_run[2] = {0.f, 0.f};
  unsigned wp[2][4][2];  // P(t-1) packed bf16 pairs, persists across barrier

  auto stageK = [&](int kt, int buf) {
#pragma unroll
    for (int i = 0; i < 4; i++) {
      const int r0 = wid * 16 + i * 4;
      const int row = r0 + k_l4;
      gload_lds16((const char*)(Kb + (b * S_ + kt * 64 + row) * D_ + h * DH_) +
                      ((k_c ^ (row & 7)) << 4),
                  (char*)&lK[buf][0] + r0 * 256);
    }
  };
  auto stageV = [&](int kt, int buf) {
#pragma unroll
    for (int i = 0; i < 4; i++) {
      const int r0 = wid * 32 + i * 8;
      const int row = r0 + v_l3;
      gload_lds16((const char*)(Vt + ((b * H_ + h) * DH_ + row) * S_ + kt * 64) +
                      ((v_c ^ (row & 7)) << 4),
                  (char*)&lV[buf][0] + r0 * 128);
    }
  };

  stageK(0, 0);
  stageV(0, 0);
  __syncthreads();

  for (int kt = 0; kt < NT_; ++kt) {
    const int kcur = kt & 1;
    if (kt + 1 < NT_) { stageK(kt + 1, kcur ^ 1); stageV(kt + 1, (kt + 1) % 3); }

    // ---- QK(t) + PV(t-1): two independent MFMA streams, one burst ----
    f32x4 s[2][4];
#pragma unroll
    for (int qi = 0; qi < 2; qi++)
#pragma unroll
      for (int kn = 0; kn < 4; kn++) s[qi][kn] = (f32x4){0.f, 0.f, 0.f, 0.f};
    __builtin_amdgcn_s_setprio(1);
#pragma unroll
    for (int kk = 0; kk < 4; kk++) {
      s16x8 kf[4];
#pragma unroll
      for (int kn = 0; kn < 4; kn++) {
        int row = kn * 16 + lc;
        kf[kn] = *(const s16x8*)((const char*)&lK[kcur][0] + row * 256 +
                                 ((kk * 64 + g * 16) ^ ((row & 7) << 4)));
      }
#pragma unroll
      for (int qi = 0; qi < 2; qi++)
#pragma unroll
        for (int kn = 0; kn < 4; kn++) s[qi][kn] = mfma16(kf[kn], qf[qi][kk], s[qi][kn]);
    }
    if (kt > 0) {  // PV(t-1): reads lV[(kt-1)%3]; stage writes lV[(kt+1)%3] - disjoint
      const int vprev = (kt + 2) % 3;
#pragma unroll
      for (int kk = 0; kk < 2; kk++) {
        s16x8 pf[2];
#pragma unroll
        for (int qi = 0; qi < 2; qi++) {
          union { unsigned u[4]; s16x8 v; } pu;
          pu.u[0] = wp[qi][2 * kk][0];
          pu.u[1] = wp[qi][2 * kk][1];
          pu.u[2] = wp[qi][2 * kk + 1][0];
          pu.u[3] = wp[qi][2 * kk + 1][1];
          pf[qi] = pu.v;
        }
#pragma unroll
        for (int dn = 0; dn < 8; dn++) {
          int vrow = dn * 16 + lc;
          s16x8 vf = *(const s16x8*)((const char*)&lV[vprev][0] + vrow * 128 +
                                     ((kk * 64 + g * 16) ^ ((vrow & 7) << 4)));
#pragma unroll
          for (int qi = 0; qi < 2; qi++) acco[qi][dn] = mfma16(vf, pf[qi], acco[qi][dn]);
        }
      }
    }
    __builtin_amdgcn_s_setprio(0);

    // ---- SM(t): max + defer-rescale (acco now includes PV(t-1)) ----
    float mx[2];
    int trig = 0;
#pragma unroll
    for (int qi = 0; qi < 2; qi++) {
      float m01 = fmaxf(fmaxf(s[qi][0][0], s[qi][0][1]), fmaxf(s[qi][0][2], s[qi][0][3]));
      float m1 = fmaxf(fmaxf(s[qi][1][0], s[qi][1][1]), fmaxf(s[qi][1][2], s[qi][1][3]));
      float m2 = fmaxf(fmaxf(s[qi][2][0], s[qi][2][1]), fmaxf(s[qi][2][2], s[qi][2][3]));
      float m3 = fmaxf(fmaxf(s[qi][3][0], s[qi][3][1]), fmaxf(s[qi][3][2], s[qi][3][3]));
      float m = fmaxf(fmaxf(m01, m1), fmaxf(m2, m3));
      m = fmaxf(m, __shfl_xor(m, 16));
      m = fmaxf(m, __shfl_xor(m, 32));
      mx[qi] = m;
      trig |= (m > m_run[qi] + 8.0f);
    }
    if (__any(trig)) {
#pragma unroll
      for (int qi = 0; qi < 2; qi++) {
        float mn = fmaxf(m_run[qi], mx[qi]);
        float fsc = exp2f(m_run[qi] - mn);
        m_run[qi] = mn;
        l_run[qi] *= fsc;
#pragma unroll
        for (int dn = 0; dn < 8; dn++)
#pragma unroll
          for (int r = 0; r < 4; r++) acco[qi][dn][r] *= fsc;
      }
    }

    // ---- P(t) = exp2(s - m): pack into wp for next-iteration PV ----
#pragma unroll
    for (int qi = 0; qi < 2; qi++) {
      float ls = 0.f;
#pragma unroll
      for (int kn = 0; kn < 4; kn++) {
        float p0 = exp2f(s[qi][kn][0] - m_run[qi]);
        float p1 = exp2f(s[qi][kn][1] - m_run[qi]);
        float p2 = exp2f(s[qi][kn][2] - m_run[qi]);
        float p3 = exp2f(s[qi][kn][3] - m_run[qi]);
        ls += (p0 + p1) + (p2 + p3);
        wp[qi][kn][0] = cvtpk2(p0, p1);
        wp[qi][kn][1] = cvtpk2(p2, p3);
      }
      ls += __shfl_xor(ls, 16);
      ls += __shfl_xor(ls, 32);
      l_run[qi] += ls;
    }
    __syncthreads();  // drains staging; protects lK/lV slot reuse
  }

  // ---- epilogue: PV(NT-1) ----
  {
    const int vprev = (NT_ + 2) % 3;
    __builtin_amdgcn_s_setprio(1);
#pragma unroll
    for (int kk = 0; kk < 2; kk++) {
      s16x8 pf[2];
#pragma unroll
      for (int qi = 0; qi < 2; qi++) {
        union { unsigned u[4]; s16x8 v; } pu;
        pu.u[0] = wp[qi][2 * kk][0];
        pu.u[1] = wp[qi][2 * kk][1];
        pu.u[2] = wp[qi][2 * kk + 1][0];
        pu.u[3] = wp[qi][2 * kk + 1][1];
        pf[qi] = pu.v;
      }
#pragma unroll
      for (int dn = 0; dn < 8; dn++) {
        int vrow = dn * 16 + lc;
        s16x8 vf = *(const s16x8*)((const char*)&lV[vprev][0] + vrow * 128 +
                                   ((kk * 64 + g * 16) ^ ((vrow & 7) << 4)));
#pragma unroll
        for (int qi = 0; qi < 2; qi++) acco[qi][dn] = mfma16(vf, pf[qi], acco[qi][dn]);
      }
    }
    __builtin_amdgcn_s_setprio(0);
  }
  __syncthreads();

  char* tb = (char*)&lK[0][0] + wid * 8192;
#pragma unroll
  for (int qi = 0; qi < 2; qi++) {
    float inv = 1.f / l_run[qi];
    int row = qi * 16 + lc;
#pragma unroll
    for (int dn = 0; dn < 8; dn++) {
      unsigned lo = cvtpk2(acco[qi][dn][0] * inv, acco[qi][dn][1] * inv);
      unsigned hi = cvtpk2(acco[qi][dn][2] * inv, acco[qi][dn][3] * inv);
      unsigned long long pk = (unsigned long long)lo | ((unsigned long long)hi << 32);
      *(unsigned long long*)(tb + row * 256 + ((dn * 32 + g * 8) ^ ((row & 7) << 4))) = pk;
    }
  }
  __syncthreads();
#pragma unroll
  for (int i = 0; i < 8; i++) {
    const int row = i * 4 + (lane >> 4);
    const int chunk = lane & 15;
    s16x8 vv = *(const s16x8*)(tb + row * 256 + ((chunk * 16) ^ ((row & 7) << 4)));
    *(s16x8*)(zatt + ((long)(b * S_ + q0 + wid * 32 + row)) * 2048 + h * DH_ + chunk * 8) = vv;
  }
  if (g == 0) {
#pragma unroll
    for (int qi = 0; qi < 2; qi++) {
      int q = q0 + wid * 32 + qi * 16 + lc;
      Mo[(long)(b * H_ + h) * S_ + q] = m_run[qi];
      Lo[(long)(b * H_ + h) * S_ + q] = l_run[qi];
    }
  }
}

// ---------------- attn_weights, 2-head pipelined accumulate ----------------
// QK(h) MFMAs issue, then accum of head h-1 (completed scores) overlaps them.
// h-loop fully unrolled so the parity-indexed score buffer stays in registers.
__global__ __launch_bounds__(256) void attw_kernel(
    const unsigned short* __restrict__ Q, const unsigned short* __restrict__ Kb,
    const float* __restrict__ Mo, const float* __restrict__ Lo,
    float* __restrict__ AW) {
  __shared__ unsigned short lK[2][128 * 128];
  __shared__ float lm[H_][128], winv[H_][128];
  const int t = threadIdx.x, wid = t >> 6, lane = t & 63;
  const int g = lane >> 4, lc = lane & 15;
  const int f = blockIdx.x + 16 * (blockIdx.y + 16 * blockIdx.z);
  const int xcd = f & 7, i_ = f >> 3;
  const int grp = (i_ >> 4) * 8 + xcd;
  const int b = grp >> 4, k0 = (grp & 15) * 128, q0 = (i_ & 15) * 128;
  const int k_l4 = lane >> 4, k_c = lane & 15;

  for (int i = t; i < H_ * 128; i += 256) {
    int h = i >> 7, qq = i & 127;
    lm[h][qq] = Mo[(long)(b * H_ + h) * S_ + q0 + qq];
    winv[h][qq] = 0.125f / Lo[(long)(b * H_ + h) * S_ + q0 + qq];
  }

  auto stageK = [&](int h, int buf) {
#pragma unroll
    for (int i = 0; i < 8; i++) {
      const int r0 = wid * 32 + i * 4;
      const int row = r0 + k_l4;
      gload_lds16((const char*)(Kb + ((long)(b * S_ + k0 + row)) * D_ + h * DH_) +
                      ((k_c ^ (row & 7)) << 4),
                  (char*)&lK[buf][0] + r0 * 256);
    }
  };

  f32x4 acc[2][8];
#pragma unroll
  for (int qi = 0; qi < 2; qi++)
#pragma unroll
    for (int kn = 0; kn < 8; kn++) acc[qi][kn] = (f32x4){0.f, 0.f, 0.f, 0.f};

  f32x4 sb[2][2][8];  // [h parity][qi][kn] -- static indices after full unroll

  stageK(0, 0);
  __syncthreads();

#pragma unroll
  for (int h = 0; h < H_; ++h) {
    const int cur = h & 1;
    if (h + 1 < H_) stageK(h + 1, cur ^ 1);
#pragma unroll
    for (int qi = 0; qi < 2; qi++)
#pragma unroll
      for (int kn = 0; kn < 8; kn++) sb[cur][qi][kn] = (f32x4){0.f, 0.f, 0.f, 0.f};
    __builtin_amdgcn_s_setprio(1);
#pragma unroll
    for (int kk = 0; kk < 4; kk++) {
      s16x8 qa[2];
#pragma unroll
      for (int qi = 0; qi < 2; qi++)
        qa[qi] = *(const s16x8*)(Q +
            ((long)(b * S_ + q0 + wid * 32 + qi * 16 + lc)) * D_ + h * DH_ + kk * 32 + g * 8);
#pragma unroll
      for (int kn = 0; kn < 8; kn++) {
        int row = kn * 16 + lc;
        s16x8 kf = *(const s16x8*)((const char*)&lK[cur][0] + row * 256 +
                                   ((kk * 64 + g * 16) ^ ((row & 7) << 4)));
#pragma unroll
        for (int qi = 0; qi < 2; qi++)
          sb[cur][qi][kn] = mfma16(qa[qi], kf, sb[cur][qi][kn]);
      }
    }
    // accum head h-1 (completed scores) while QK(h) MFMAs are in flight
    if (h > 0) {
#pragma unroll
      for (int qi = 0; qi < 2; qi++)
#pragma unroll
        for (int kn = 0; kn < 8; kn++)
#pragma unroll
          for (int r = 0; r < 4; r++) {
            int qq = wid * 32 + qi * 16 + g * 4 + r;
            acc[qi][kn][r] += exp2f(sb[cur ^ 1][qi][kn][r] - lm[h - 1][qq]) *
                              winv[h - 1][qq];
          }
    }
    __builtin_amdgcn_s_setprio(0);
    __syncthreads();
  }
  // epilogue: accum head H-1
#pragma unroll
  for (int qi = 0; qi < 2; qi++)
#pragma unroll
    for (int kn = 0; kn < 8; kn++)
#pragma unroll
      for (int r = 0; r < 4; r++) {
        int qq = wid * 32 + qi * 16 + g * 4 + r;
        acc[qi][kn][r] += exp2f(sb[(H_ - 1) & 1][qi][kn][r] - lm[H_ - 1][qq]) *
                          winv[H_ - 1][qq];
      }

#pragma unroll
  for (int qi = 0; qi < 2; qi++)
#pragma unroll
    for (int kn = 0; kn < 8; kn++)
#pragma unroll
      for (int r = 0; r < 4; r++) {
        long q = q0 + wid * 32 + qi * 16 + g * 4 + r;
        int k = k0 + kn * 16 + lc;
        AW[((long)b * S_ + q) * S_ + k] = acc[qi][kn][r];
      }
}

__global__ void signal_kernel(float* out, float v) { out[0] = v; }

extern "C" void kernel_launch(void* const* d_in, const int* in_sizes, int n_in,
                              void* d_out, int out_size, void* d_ws, size_t ws_size,
                              hipStream_t stream) {
  constexpr size_t OFF_XB = 0;              // 16 MB
  constexpr size_t OFF_W = 16777216ULL;     // bf16 weights
  constexpr size_t OFF_T = 39845888ULL;     // 16 MB bf16 intermediate (t1)
  constexpr size_t OFF_HR = 56623104ULL;    // 32 MB (wct f32 partials / bf16 hraw)
  constexpr size_t OFF_Z = 90177536ULL;     // 32 MB bf16 [8192,2048]  (hsel | ctx)
  constexpr size_t OFF_Q = 123731968ULL;
  constexpr size_t OFF_K = 140509184ULL;
  constexpr size_t OFF_V = 157286400ULL;
  constexpr size_t OFF_VT = 174063616ULL;
  constexpr size_t OFF_M = 190840832ULL;
  constexpr size_t OFF_L = 191102976ULL;
  constexpr size_t OFF_CNT = 191365120ULL;
  constexpr size_t OFF_RIDX = 191365184ULL;
  constexpr size_t OFF_BC = OFF_RIDX + 2ULL * MTOT * 4;   // bias_c (4KB)
  constexpr size_t OFF_ACT = OFF_BC + 4096;               // active rows
  constexpr size_t OFF_ACT2 = OFF_ACT + MTOT * 4;         // level>=2 rows
  constexpr size_t WS_NEED = OFF_ACT2 + MTOT * 4;

  if (ws_size < WS_NEED) {
    signal_kernel<<<1, 1, 0, stream>>>((float*)d_out, (float)ws_size);
    return;
  }
  const float* x = (const float*)d_in[0];
  const int* levels = (const int*)d_in[1];
  const float* p1w = (const float*)d_in[2];
  const float* p1b = (const float*)d_in[3];
  const float* p2w = (const float*)d_in[4];
  const float* p2b = (const float*)d_in[5];
  const float* lng = (const float*)d_in[6];
  const float* lnb = (const float*)d_in[7];
  const float* wq = (const float*)d_in[8];
  const float* bq = (const float*)d_in[9];
  const float* wk = (const float*)d_in[10];
  const float* bk = (const float*)d_in[11];
  const float* wv = (const float*)d_in[12];
  const float* bv = (const float*)d_in[13];
  const float* wo = (const float*)d_in[14];
  const float* bo = (const float*)d_in[15];
  const float* i1w = (const float*)d_in[16];
  const float* i1b = (const float*)d_in[17];
  const float* i2w = (const float*)d_in[18];
  const float* i2b = (const float*)d_in[19];
  const float* ilng = (const float*)d_in[20];
  const float* ilnb = (const float*)d_in[21];

  char* ws = (char*)d_ws;
  unsigned short* xb = (unsigned short*)(ws + OFF_XB);
  unsigned short* p1t = (unsigned short*)(ws + OFF_W);
  unsigned short* p2t = p1t + 2 * 1048576;
  unsigned short* wqt = p2t + 2 * 1048576;   // [3072][1024] contiguous q|k|v
  unsigned short* wkt = wqt + 1048576;
  unsigned short* wvt = wkt + 1048576;
  unsigned short* wob = wvt + 1048576;       // bf16 wo, NOT transposed
  unsigned short* i1t = wob + 1048576;       // [1024][2048]
  unsigned short* i2t = i1t + 2097152;
  unsigned short* tbuf = (unsigned short*)(ws + OFF_T);  // t1 (silu out)
  float* wctp = (float*)(ws + OFF_HR);                   // [4][1024][1024] f32
  unsigned short* hraw16 = (unsigned short*)(ws + OFF_HR);  // later bf16 [8192][1024]
  unsigned short* z = (unsigned short*)(ws + OFF_Z);  // [8192][2048] hsel|ctx
  unsigned short* qb = (unsigned short*)(ws + OFF_Q);
  unsigned short* kb = (unsigned short*)(ws + OFF_K);
  unsigned short* vb = (unsigned short*)(ws + OFF_V);
  unsigned short* vt = (unsigned short*)(ws + OFF_VT);
  float* Mo = (float*)(ws + OFF_M);
  float* Lo = (float*)(ws + OFF_L);
  int* cnt = (int*)(ws + OFF_CNT);
  int* ridx = (int*)(ws + OFF_RIDX);
  float* bias_c = (float*)(ws + OFF_BC);
  int* act = (int*)(ws + OFF_ACT);
  int* act2 = (int*)(ws + OFF_ACT2);
  float* out = (float*)d_out;
  float* aw = out + (size_t)MTOT * D_;

  dim3 blk(256), blk8(512);
  hipMemsetAsync(cnt, 0, 64, stream);
  hipMemsetAsync(ridx, 0, 2 * MTOT * 4, stream);
  hipMemsetAsync(act, 0, MTOT * 4, stream);
  xconv2_kernel<<<9216, blk, 0, stream>>>(x, xb, wo, wob);
  route_kernel<<<32, blk, 0, stream>>>(levels, cnt, ridx, act, act2);
  lvl2fill_kernel<<<MTOT, blk, 0, stream>>>(act2, cnt + 3, bq, bk, bv, qb, kb, vb, z);

  WtArgs wa;
  wa.d[0] = {p1w, p1t, 1024, 0};
  wa.d[1] = {p1w + 1048576, p1t + 1048576, 1024, 0};
  wa.d[2] = {p2w, p2t, 1024, 0};
  wa.d[3] = {p2w + 1048576, p2t + 1048576, 1024, 0};
  wa.d[4] = {wq, wqt, 1024, 0};
  wa.d[5] = {wk, wkt, 1024, 0};
  wa.d[6] = {wv, wvt, 1024, 0};
  wa.d[7] = {i1w, i1t, 2048, 0};
  wa.d[8] = {i1w + 1048576, i1t, 2048, 1024};
  wa.d[9] = {i2w, i2t, 1024, 0};
  wtrans_all_kernel<<<dim3(32, 320), blk, 0, stream>>>(wa);
  // Wct = W2^T . wo^T, K-split x4 into wctp, then bias_c, then reduce into i1t
  wct_gemm_kernel<<<dim3(8, 32), blk, 0, stream>>>(i1t + 1024, wob, wctp);
  biascomb_kernel<<<1024, blk, 0, stream>>>(i1t, bo, i1b, bias_c);
  wct_reduce_kernel<<<2048, blk, 0, stream>>>(wctp, i1t);

  // merged MoE processor stage (8-wave blocks)
  gemm8_moe_kernel<1><<<dim3(8, 64), blk8, 0, stream>>>(xb, 1024, p1t, 1024, p1b,
                                                        tbuf, 1024, 1024, 1, ridx, cnt);
  gemm8_moe_kernel<0><<<dim3(8, 64), blk8, 0, stream>>>(tbuf, 1024, p2t, 1024, p2b,
                                                        hraw16, 1024, 1024, 0, ridx, cnt);
  ln_moe_kernel<<<8192, blk, 0, stream>>>(hraw16, ridx, cnt, lng, lnb, z, 2048);

  gemm_qkv_kernel<<<dim3(24, 64), blk, 0, stream>>>(z, 2048, wqt, bq, bk, bv, qb, kb, vb,
                                                    act, cnt + 2);
  vtrans_kernel<<<dim3(64, 32, 4), blk, 0, stream>>>(vb, vt);
  flash_kernel<<<dim3(16, 8, 4), blk, 0, stream>>>(qb, kb, vt, z + 1024, Mo, Lo);
  attw_kernel<<<dim3(16, 16, 4), blk, 0, stream>>>(qb, kb, Mo, Lo, aw);
  gemm8_kernel<3><<<dim3(8, 64), blk8, 0, stream>>>(z, 2048, i1t, 2048, bias_c, 1.0f, tbuf,
                                                    1024, 2048, 1);
  gemm8_kernel<4><<<dim3(8, 64), blk8, 0, stream>>>(tbuf, 1024, i2t, 1024, i2b, 1.0f, hraw16,
                                                    1024, 1024, 0);
  ln_kernel<<<8192, blk, 0, stream>>>(hraw16, ilng, ilnb, out);
}

// Round 18
// 439.001 us; speedup vs baseline: 1.1824x; 1.1824x over previous
//
#include <hip/hip_runtime.h>
#include <cstdint>
#include <cstddef>

#define B_ 4
#define S_ 2048
#define D_ 1024
#define H_ 8
#define DH_ 128
#define MTOT 8192
#define NT_ 32
#define SCALE2 (0.08838834764831845f * 1.4426950408889634f)  // 1/sqrt(128) * log2(e)

typedef __attribute__((ext_vector_type(8))) short s16x8;
typedef __attribute__((ext_vector_type(4))) float f32x4;
typedef __attribute__((ext_vector_type(8))) __bf16 bf16x8;

static __device__ __forceinline__ f32x4 mfma16(s16x8 a, s16x8 b, f32x4 c) {
  return __builtin_amdgcn_mfma_f32_16x16x32_bf16(
      __builtin_bit_cast(bf16x8, a), __builtin_bit_cast(bf16x8, b), c, 0, 0, 0);
}
static __device__ __forceinline__ unsigned short f2bf(float f) {
  unsigned u = __builtin_bit_cast(unsigned, f);
  u += 0x7fffu + ((u >> 16) & 1u);
  return (unsigned short)(u >> 16);
}
static __device__ __forceinline__ float bf2f(unsigned short u) {
  return __builtin_bit_cast(float, (unsigned)u << 16);
}
// packed f32x2 -> bf16x2 (lo = a, hi = b)
static __device__ __forceinline__ unsigned cvtpk2(float a, float b) {
  unsigned r;
  asm("v_cvt_pk_bf16_f32 %0, %1, %2" : "=v"(r) : "v"(a), "v"(b));
  return r;
}
// async global->LDS, 16B per lane; LDS dest = wave-uniform base + lane*16
static __device__ __forceinline__ void gload_lds16(const void* g, void* l) {
  __builtin_amdgcn_global_load_lds(
      (__attribute__((address_space(1))) void*)(void*)(g),
      (__attribute__((address_space(3))) void*)(l), 16, 0, 0);
}

// ---------------- x f32 -> bf16 AND wo f32 -> bf16, one launch ----------------
__global__ __launch_bounds__(256) void xconv2_kernel(const float* __restrict__ x,
                                                     unsigned short* __restrict__ xb,
                                                     const float* __restrict__ wo,
                                                     unsigned short* __restrict__ wob) {
  if (blockIdx.x < 8192) {
    long i = ((long)blockIdx.x * 256 + threadIdx.x) * 4;
    float4 v = *(const float4*)(x + i);
    ushort4 o;
    o.x = f2bf(v.x); o.y = f2bf(v.y); o.z = f2bf(v.z); o.w = f2bf(v.w);
    *(ushort4*)(xb + i) = o;
  } else {
    long i = ((long)(blockIdx.x - 8192) * 256 + threadIdx.x) * 4;
    float4 v = *(const float4*)(wo + i);
    ushort4 o;
    o.x = f2bf(v.x); o.y = f2bf(v.y); o.z = f2bf(v.z); o.w = f2bf(v.w);
    *(ushort4*)(wob + i) = o;
  }
}

// ---------------- routing, wave-aggregated (1 atomic per wave per category) ---
__global__ __launch_bounds__(256) void route_kernel(const int* __restrict__ levels,
                                                    int* __restrict__ cnt,
                                                    int* __restrict__ ridx,
                                                    int* __restrict__ act,
                                                    int* __restrict__ act2) {
  const int row = blockIdx.x * 256 + threadIdx.x;
  const int lane = threadIdx.x & 63;
  const int lvl = levels[row];
  const unsigned long long lmlt = (lane == 63) ? ~0ULL >> 1 : (1ULL << lane) - 1;

#pragma unroll
  for (int c = 0; c < 2; c++) {
    bool pred = (lvl == c);
    unsigned long long mask = __ballot(pred);
    int total = __popcll(mask);
    if (total) {
      int leader = __ffsll((long long)mask) - 1;
      int base = 0;
      if (lane == leader) base = atomicAdd(&cnt[c], total);
      base = __shfl(base, leader);
      if (pred) ridx[c * MTOT + base + __popcll(mask & lmlt)] = row;
    }
  }
  {
    bool pred = (lvl < 2);
    unsigned long long mask = __ballot(pred);
    int total = __popcll(mask);
    if (total) {
      int leader = __ffsll((long long)mask) - 1;
      int base = 0;
      if (lane == leader) base = atomicAdd(&cnt[2], total);
      base = __shfl(base, leader);
      if (pred) act[base + __popcll(mask & lmlt)] = row;
    }
    unsigned long long mask2 = ~mask;
    int total2 = 64 - total;
    if (total2) {
      int leader2 = __ffsll((long long)mask2) - 1;
      int base2 = 0;
      if (lane == leader2) base2 = atomicAdd(&cnt[3], total2);
      base2 = __shfl(base2, leader2);
      if (!pred) act2[base2 + __popcll(mask2 & lmlt)] = row;
    }
  }
}

// ---------------- level>=2 rows: q/k/v = bias, hsel half of z = 0 -------------
__global__ __launch_bounds__(256) void lvl2fill_kernel(
    const int* __restrict__ act2, const int* __restrict__ cntp,
    const float* __restrict__ bq, const float* __restrict__ bk,
    const float* __restrict__ bv,
    unsigned short* __restrict__ qb, unsigned short* __restrict__ kb,
    unsigned short* __restrict__ vb, unsigned short* __restrict__ z) {
  const int idx = blockIdx.x;
  if (idx >= *cntp) return;
  const long row = act2[idx];
  const int t = threadIdx.x;
  const float4 q4 = *(const float4*)(bq + t * 4);
  const float4 k4 = *(const float4*)(bk + t * 4);
  const float4 v4 = *(const float4*)(bv + t * 4);
  ushort4 qo, ko, vo;
  qo.x = f2bf(q4.x * SCALE2); qo.y = f2bf(q4.y * SCALE2);
  qo.z = f2bf(q4.z * SCALE2); qo.w = f2bf(q4.w * SCALE2);
  ko.x = f2bf(k4.x); ko.y = f2bf(k4.y); ko.z = f2bf(k4.z); ko.w = f2bf(k4.w);
  vo.x = f2bf(v4.x); vo.y = f2bf(v4.y); vo.z = f2bf(v4.z); vo.w = f2bf(v4.w);
  *(ushort4*)(qb + row * 1024 + t * 4) = qo;
  *(ushort4*)(kb + row * 1024 + t * 4) = ko;
  *(ushort4*)(vb + row * 1024 + t * 4) = vo;
  *(ushort4*)(z + row * 2048 + t * 4) = (ushort4){0, 0, 0, 0};
}

// ---------------- all weight transposes in one launch ----------------
struct WtDesc { const float* src; unsigned short* dst; long dst_ld; long dst_off; };
struct WtArgs { WtDesc d[10]; };
__global__ __launch_bounds__(256) void wtrans_all_kernel(WtArgs a) {
  __shared__ unsigned short tile[32][33];
  const int wi = blockIdx.y >> 5;
  const WtDesc de = a.d[wi];
  int r0 = (blockIdx.y & 31) * 32, c0 = blockIdx.x * 32;
  int tr = threadIdx.x >> 5, tc = threadIdx.x & 31;
#pragma unroll
  for (int i = 0; i < 4; i++)
    tile[tr + i * 8][tc] = f2bf(de.src[(long)(r0 + tr + i * 8) * 1024 + c0 + tc]);
  __syncthreads();
#pragma unroll
  for (int i = 0; i < 4; i++)
    de.dst[(long)(c0 + tr + i * 8) * de.dst_ld + de.dst_off + r0 + tc] = tile[tc][tr + i * 8];
}

// ---------------- v bf16 [B,S,H,DH] -> [B,H,DH,S'] with key-slot permutation --
__global__ __launch_bounds__(256) void vtrans_kernel(const unsigned short* __restrict__ V,
                                                     unsigned short* __restrict__ Vt) {
  __shared__ unsigned short tile[32][33];
  int b = blockIdx.z;
  int h = blockIdx.y >> 2, d0 = (blockIdx.y & 3) * 32;
  int s0 = blockIdx.x * 32;
  int tr = threadIdx.x >> 5, tc = threadIdx.x & 31;
#pragma unroll
  for (int i = 0; i < 4; i++)
    tile[tr + i * 8][tc] = V[((long)(b * S_) + s0 + tr + i * 8) * D_ + h * DH_ + d0 + tc];
  __syncthreads();
  const int sk = s0 + tc;
  const int k6 = sk & 63;
  const int slot = ((k6 >> 5) << 5) | (((k6 >> 2) & 3) << 3) | (((k6 >> 4) & 1) << 2) | (k6 & 3);
  const int ss = (sk & ~63) | slot;
#pragma unroll
  for (int i = 0; i < 4; i++)
    Vt[((long)(b * H_ + h) * DH_ + d0 + tr + i * 8) * S_ + ss] = tile[tc][tr + i * 8];
}

// ---------------- 8-wave GEMM: 128^2 tile, 512 thr ----------------
template <int TAG>
__global__ __launch_bounds__(512) void gemm8_kernel(
    const unsigned short* __restrict__ A, int lda,
    const unsigned short* __restrict__ Wt, int ldw,
    const float* __restrict__ bias, float oscale,
    unsigned short* __restrict__ Cb, int ldc,
    int K, int do_silu) {
  __shared__ unsigned short lA[128 * 64];
  __shared__ unsigned short lB[128 * 64];
  const int t = threadIdx.x;
  const int wid = t >> 6, lane = t & 63;
  const int g = lane >> 4, lc = lane & 15;
  const int wr = wid >> 1, wc = wid & 1;   // 4x2 wave grid: 32-row x 64-col subtiles
  const int nwg = gridDim.x * gridDim.y;
  int flat = blockIdx.x + gridDim.x * blockIdx.y;
  flat = (flat & 7) * (nwg >> 3) + (flat >> 3);
  const int m0 = (flat / gridDim.x) * 128;
  const int n0 = (flat % gridDim.x) * 128;
  const int srow = lane >> 3, scol = lane & 7;
  const int sxor = (scol ^ srow) << 4;

  f32x4 acc[2][4];
#pragma unroll
  for (int i = 0; i < 2; i++)
#pragma unroll
    for (int j = 0; j < 4; j++) acc[i][j] = (f32x4){0.f, 0.f, 0.f, 0.f};

  const int nk = K >> 6;
  for (int kt = 0; kt < nk; ++kt) {
    const int k0 = kt << 6;
#pragma unroll
    for (int i = 0; i < 2; i++) {
      const int r0 = wid * 16 + i * 8;
      gload_lds16((const char*)(A + (m0 + r0 + srow) * (long)lda + k0) + sxor,
                  (char*)lA + r0 * 128);
      gload_lds16((const char*)(Wt + (n0 + r0 + srow) * (long)ldw + k0) + sxor,
                  (char*)lB + r0 * 128);
    }
    __syncthreads();
#pragma unroll
    for (int kk = 0; kk < 2; kk++) {
      s16x8 af[2], bfr[4];
#pragma unroll
      for (int i = 0; i < 2; i++) {
        int row = wr * 32 + i * 16 + lc;
        af[i] = *(const s16x8*)((const char*)lA + row * 128 +
                                ((kk * 64 + g * 16) ^ ((row & 7) << 4)));
      }
#pragma unroll
      for (int j = 0; j < 4; j++) {
        int row = wc * 64 + j * 16 + lc;
        bfr[j] = *(const s16x8*)((const char*)lB + row * 128 +
                                 ((kk * 64 + g * 16) ^ ((row & 7) << 4)));
      }
#pragma unroll
      for (int i = 0; i < 2; i++)
#pragma unroll
        for (int j = 0; j < 4; j++) acc[i][j] = mfma16(af[i], bfr[j], acc[i][j]);
    }
    __syncthreads();
  }
#pragma unroll
  for (int i = 0; i < 2; i++) {
    const long rbase = m0 + wr * 32 + i * 16 + g * 4;
#pragma unroll
    for (int j = 0; j < 4; j++) {
      const int col = n0 + wc * 64 + j * 16 + lc;
      const float bv = bias[col];
#pragma unroll
      for (int r = 0; r < 4; r++) {
        float v = (acc[i][j][r] + bv) * oscale;
        if (do_silu) v = v / (1.f + __expf(-v));
        Cb[(rbase + r) * (long)ldc + col] = f2bf(v);
      }
    }
  }
}

// ---------------- 8-wave merged MoE GEMM ----------------
template <int RMAP>
__global__ __launch_bounds__(512) void gemm8_moe_kernel(
    const unsigned short* __restrict__ A, int lda,
    const unsigned short* __restrict__ Wt0, int ldw,
    const float* __restrict__ bias0,
    unsigned short* __restrict__ Cb, int ldc,
    int K, int do_silu, const int* __restrict__ ridx, const int* __restrict__ cnt2) {
  __shared__ unsigned short lA[128 * 64];
  __shared__ unsigned short lB[128 * 64];
  const int t = threadIdx.x;
  const int wid = t >> 6, lane = t & 63;
  const int g = lane >> 4, lc = lane & 15;
  const int wr = wid >> 1, wc = wid & 1;
  const int nwg = gridDim.x * gridDim.y;
  int flat = blockIdx.x + gridDim.x * blockIdx.y;
  flat = (flat & 7) * (nwg >> 3) + (flat >> 3);
  const int m0 = (flat / gridDim.x) * 128;
  const int n0 = (flat % gridDim.x) * 128;
  const int lvl = m0 >> 12;
  const int lm0 = m0 & 4095;
  if (lm0 >= cnt2[lvl]) return;
  const unsigned short* Wt = Wt0 + (long)lvl * 1048576;
  const float* bias = bias0 + lvl * 1024;
  const int srow = lane >> 3, scol = lane & 7;
  const int sxor = (scol ^ srow) << 4;

  const unsigned short* abase[2];
#pragma unroll
  for (int i = 0; i < 2; i++) {
    int ar;
    if (RMAP) ar = ridx[lvl * MTOT + lm0 + wid * 16 + i * 8 + srow];
    else ar = m0 + wid * 16 + i * 8 + srow;
    abase[i] = A + (long)ar * lda;
  }

  f32x4 acc[2][4];
#pragma unroll
  for (int i = 0; i < 2; i++)
#pragma unroll
    for (int j = 0; j < 4; j++) acc[i][j] = (f32x4){0.f, 0.f, 0.f, 0.f};

  const int nk = K >> 6;
  for (int kt = 0; kt < nk; ++kt) {
    const int k0 = kt << 6;
#pragma unroll
    for (int i = 0; i < 2; i++) {
      const int r0 = wid * 16 + i * 8;
      gload_lds16((const char*)(abase[i] + k0) + sxor, (char*)lA + r0 * 128);
      gload_lds16((const char*)(Wt + (n0 + r0 + srow) * (long)ldw + k0) + sxor,
                  (char*)lB + r0 * 128);
    }
    __syncthreads();
#pragma unroll
    for (int kk = 0; kk < 2; kk++) {
      s16x8 af[2], bfr[4];
#pragma unroll
      for (int i = 0; i < 2; i++) {
        int row = wr * 32 + i * 16 + lc;
        af[i] = *(const s16x8*)((const char*)lA + row * 128 +
                                ((kk * 64 + g * 16) ^ ((row & 7) << 4)));
      }
#pragma unroll
      for (int j = 0; j < 4; j++) {
        int row = wc * 64 + j * 16 + lc;
        bfr[j] = *(const s16x8*)((const char*)lB + row * 128 +
                                 ((kk * 64 + g * 16) ^ ((row & 7) << 4)));
      }
#pragma unroll
      for (int i = 0; i < 2; i++)
#pragma unroll
        for (int j = 0; j < 4; j++) acc[i][j] = mfma16(af[i], bfr[j], acc[i][j]);
    }
    __syncthreads();
  }
#pragma unroll
  for (int i = 0; i < 2; i++) {
    const long rbase = m0 + wr * 32 + i * 16 + g * 4;
#pragma unroll
    for (int j = 0; j < 4; j++) {
      const int col = n0 + wc * 64 + j * 16 + lc;
      const float bv = bias[col];
#pragma unroll
      for (int r = 0; r < 4; r++) {
        float v = acc[i][j][r] + bv;
        if (do_silu) v = v / (1.f + __expf(-v));
        Cb[(rbase + r) * (long)ldc + col] = f2bf(v);
      }
    }
  }
}

// ---------------- Wct partial GEMM ----------------
__global__ __launch_bounds__(256) void wct_gemm_kernel(
    const unsigned short* __restrict__ A,   // i1t+1024, lda 2048
    const unsigned short* __restrict__ Wb,  // wob, ldw 1024
    float* __restrict__ Cf) {               // [4][1024][1024]
  __shared__ unsigned short lA[128 * 64];
  __shared__ unsigned short lB[128 * 64];
  const int t = threadIdx.x;
  const int wid = t >> 6, lane = t & 63;
  const int g = lane >> 4, lc = lane & 15;
  const int wr = wid >> 1, wc = wid & 1;
  const int chunk = blockIdx.y >> 3;
  const int m0 = (blockIdx.y & 7) * 128;
  const int n0 = blockIdx.x * 128;
  const unsigned short* A0 = A + chunk * 256;
  const unsigned short* W0 = Wb + chunk * 256;
  float* C0 = Cf + (long)chunk * 1048576;
  const int srow = lane >> 3, scol = lane & 7;
  const int sxor = (scol ^ srow) << 4;

  f32x4 acc[4][4];
#pragma unroll
  for (int i = 0; i < 4; i++)
#pragma unroll
    for (int j = 0; j < 4; j++) acc[i][j] = (f32x4){0.f, 0.f, 0.f, 0.f};

  for (int kt = 0; kt < 4; ++kt) {
    const int k0 = kt << 6;
#pragma unroll
    for (int i = 0; i < 4; i++) {
      const int r0 = wid * 32 + i * 8;
      gload_lds16((const char*)(A0 + (m0 + r0 + srow) * 2048L + k0) + sxor,
                  (char*)lA + r0 * 128);
      gload_lds16((const char*)(W0 + (n0 + r0 + srow) * 1024L + k0) + sxor,
                  (char*)lB + r0 * 128);
    }
    __syncthreads();
#pragma unroll
    for (int kk = 0; kk < 2; kk++) {
      s16x8 af[4], bfr[4];
#pragma unroll
      for (int i = 0; i < 4; i++) {
        int row = wr * 64 + i * 16 + lc;
        af[i] = *(const s16x8*)((const char*)lA + row * 128 +
                                ((kk * 64 + g * 16) ^ ((row & 7) << 4)));
      }
#pragma unroll
      for (int j = 0; j < 4; j++) {
        int row = wc * 64 + j * 16 + lc;
        bfr[j] = *(const s16x8*)((const char*)lB + row * 128 +
                                 ((kk * 64 + g * 16) ^ ((row & 7) << 4)));
      }
#pragma unroll
      for (int i = 0; i < 4; i++)
#pragma unroll
        for (int j = 0; j < 4; j++) acc[i][j] = mfma16(af[i], bfr[j], acc[i][j]);
    }
    __syncthreads();
  }
#pragma unroll
  for (int i = 0; i < 4; i++) {
    const long rbase = m0 + wr * 64 + i * 16 + g * 4;
#pragma unroll
    for (int j = 0; j < 4; j++) {
      const int col = n0 + wc * 64 + j * 16 + lc;
#pragma unroll
      for (int r = 0; r < 4; r++) C0[(rbase + r) * 1024L + col] = acc[i][j][r];
    }
  }
}

// ---------------- wct reduce: sum 4 K-chunks -> bf16 into i1t cols [1024:2048)
__global__ __launch_bounds__(256) void wct_reduce_kernel(
    const float* __restrict__ hraw, unsigned short* __restrict__ i1t) {
  long e = ((long)blockIdx.x * 256 + threadIdx.x) * 2;
  float a0 = hraw[e] + hraw[e + 1048576] + hraw[e + 2097152] + hraw[e + 3145728];
  float a1 = hraw[e + 1] + hraw[e + 1 + 1048576] + hraw[e + 1 + 2097152] +
             hraw[e + 1 + 3145728];
  unsigned pk = cvtpk2(a0, a1);
  long n = e >> 10, c = e & 1023;
  *(unsigned*)(i1t + n * 2048 + 1024 + c) = pk;
}

// ---------------- bias_c[n] = i1b[n] + sum_a bo[a] * W2t[n,a] (parallel) ------
__global__ __launch_bounds__(256) void biascomb_kernel(
    const unsigned short* __restrict__ i1t, const float* __restrict__ bo,
    const float* __restrict__ i1b, float* __restrict__ bias_c) {
  const int n = blockIdx.x, t = threadIdx.x;
  ushort4 w = *(const ushort4*)(i1t + (long)n * 2048 + 1024 + t * 4);
  float4 b = *(const float4*)(bo + t * 4);
  float s = bf2f(w.x) * b.x + bf2f(w.y) * b.y + bf2f(w.z) * b.z + bf2f(w.w) * b.w;
#pragma unroll
  for (int m = 32; m; m >>= 1) s += __shfl_xor(s, m);
  __shared__ float ws_[4];
  if ((t & 63) == 0) ws_[t >> 6] = s;
  __syncthreads();
  if (t == 0) bias_c[n] = i1b[n] + ws_[0] + ws_[1] + ws_[2] + ws_[3];
}

// ---------------- LayerNorm merged MoE (bf16 in): compact -> scatter ----------
__global__ __launch_bounds__(256) void ln_moe_kernel(
    const unsigned short* __restrict__ in, const int* __restrict__ ridx,
    const int* __restrict__ cnt2,
    const float* __restrict__ gg0, const float* __restrict__ bb0,
    unsigned short* __restrict__ outb, long ldo) {
  const int row = blockIdx.x;
  const int lvl = row >> 12;
  const int lrow = row & 4095;
  if (lrow >= cnt2[lvl]) return;
  const int orow = ridx[lvl * MTOT + lrow];
  const float* gg = gg0 + lvl * 1024;
  const float* bb = bb0 + lvl * 1024;
  const int t = threadIdx.x;
  const ushort4 u = *(const ushort4*)(in + (long)row * D_ + t * 4);
  float v0 = bf2f(u.x), v1 = bf2f(u.y), v2 = bf2f(u.z), v3 = bf2f(u.w);
  float s1 = v0 + v1 + v2 + v3;
  float s2 = v0 * v0 + v1 * v1 + v2 * v2 + v3 * v3;
#pragma unroll
  for (int m = 32; m; m >>= 1) {
    s1 += __shfl_xor(s1, m);
    s2 += __shfl_xor(s2, m);
  }
  __shared__ float w1[4], w2[4];
  if ((t & 63) == 0) { w1[t >> 6] = s1; w2[t >> 6] = s2; }
  __syncthreads();
  s1 = w1[0] + w1[1] + w1[2] + w1[3];
  s2 = w2[0] + w2[1] + w2[2] + w2[3];
  const float mu = s1 * (1.f / D_);
  const float var = s2 * (1.f / D_) - mu * mu;
  const float rs = rsqrtf(var + 1e-5f);
  float vv[4] = {v0, v1, v2, v3};
#pragma unroll
  for (int jj = 0; jj < 4; jj++) {
    int col = t * 4 + jj;
    float y = (vv[jj] - mu) * rs * gg[col] + bb[col];
    outb[(long)orow * ldo + col] = f2bf(y);
  }
}

// ---------------- final LayerNorm (bf16 in, f32 out) ----------------
__global__ __launch_bounds__(256) void ln_kernel(
    const unsigned short* __restrict__ in,
    const float* __restrict__ gg, const float* __restrict__ bb,
    float* __restrict__ outf) {
  const int row = blockIdx.x;
  const int t = threadIdx.x;
  const ushort4 u = *(const ushort4*)(in + (long)row * D_ + t * 4);
  float v0 = bf2f(u.x), v1 = bf2f(u.y), v2 = bf2f(u.z), v3 = bf2f(u.w);
  float s1 = v0 + v1 + v2 + v3;
  float s2 = v0 * v0 + v1 * v1 + v2 * v2 + v3 * v3;
#pragma unroll
  for (int m = 32; m; m >>= 1) {
    s1 += __shfl_xor(s1, m);
    s2 += __shfl_xor(s2, m);
  }
  __shared__ float w1[4], w2[4];
  if ((t & 63) == 0) { w1[t >> 6] = s1; w2[t >> 6] = s2; }
  __syncthreads();
  s1 = w1[0] + w1[1] + w1[2] + w1[3];
  s2 = w2[0] + w2[1] + w2[2] + w2[3];
  const float mu = s1 * (1.f / D_);
  const float var = s2 * (1.f / D_) - mu * mu;
  const float rs = rsqrtf(var + 1e-5f);
  float vv[4] = {v0, v1, v2, v3};
#pragma unroll
  for (int jj = 0; jj < 4; jj++) {
    int col = t * 4 + jj;
    outf[(long)row * D_ + col] = (vv[jj] - mu) * rs * gg[col] + bb[col];
  }
}

// ---------------- fused QKV GEMM, routed over active rows --------------------
__global__ __launch_bounds__(256) void gemm_qkv_kernel(
    const unsigned short* __restrict__ A, int lda,
    const unsigned short* __restrict__ Wt,
    const float* __restrict__ bq, const float* __restrict__ bk,
    const float* __restrict__ bv,
    unsigned short* __restrict__ qb, unsigned short* __restrict__ kb,
    unsigned short* __restrict__ vb,
    const int* __restrict__ act, const int* __restrict__ cntp) {
  __shared__ unsigned short lA[128 * 64];
  __shared__ unsigned short lB[128 * 64];
  const int t = threadIdx.x;
  const int wid = t >> 6, lane = t & 63;
  const int g = lane >> 4, lc = lane & 15;
  const int wr = wid >> 1, wc = wid & 1;
  const int nwg = gridDim.x * gridDim.y;
  int flat = blockIdx.x + gridDim.x * blockIdx.y;
  flat = (flat & 7) * (nwg >> 3) + (flat >> 3);
  const int m0 = (flat / gridDim.x) * 128;
  const int n0 = (flat % gridDim.x) * 128;
  if (m0 >= *cntp) return;
  const int srow = lane >> 3, scol = lane & 7;
  const int sxor = (scol ^ srow) << 4;

  const unsigned short* abase[4];
#pragma unroll
  for (int i = 0; i < 4; i++)
    abase[i] = A + (long)act[m0 + wid * 32 + i * 8 + srow] * lda;

  f32x4 acc[4][4];
#pragma unroll
  for (int i = 0; i < 4; i++)
#pragma unroll
    for (int j = 0; j < 4; j++) acc[i][j] = (f32x4){0.f, 0.f, 0.f, 0.f};

  for (int kt = 0; kt < 16; ++kt) {
    const int k0 = kt << 6;
#pragma unroll
    for (int i = 0; i < 4; i++) {
      const int r0 = wid * 32 + i * 8;
      gload_lds16((const char*)(abase[i] + k0) + sxor, (char*)lA + r0 * 128);
      gload_lds16((const char*)(Wt + (n0 + r0 + srow) * 1024 + k0) + sxor,
                  (char*)lB + r0 * 128);
    }
    __syncthreads();
#pragma unroll
    for (int kk = 0; kk < 2; kk++) {
      s16x8 af[4], bfr[4];
#pragma unroll
      for (int i = 0; i < 4; i++) {
        int row = wr * 64 + i * 16 + lc;
        af[i] = *(const s16x8*)((const char*)lA + row * 128 +
                                ((kk * 64 + g * 16) ^ ((row & 7) << 4)));
      }
#pragma unroll
      for (int j = 0; j < 4; j++) {
        int row = wc * 64 + j * 16 + lc;
        bfr[j] = *(const s16x8*)((const char*)lB + row * 128 +
                                 ((kk * 64 + g * 16) ^ ((row & 7) << 4)));
      }
#pragma unroll
      for (int i = 0; i < 4; i++)
#pragma unroll
        for (int j = 0; j < 4; j++) acc[i][j] = mfma16(af[i], bfr[j], acc[i][j]);
    }
    __syncthreads();
  }
  const int whichB = n0 >> 10;  // block-uniform: 0=q, 1=k, 2=v
  const float* bias = whichB == 0 ? bq : whichB == 1 ? bk : bv;
  unsigned short* Cb = whichB == 0 ? qb : whichB == 1 ? kb : vb;
  const float oscale = whichB == 0 ? (float)SCALE2 : 1.0f;
  const int nb = n0 & 1023;
#pragma unroll
  for (int i = 0; i < 4; i++) {
    const int ribase = m0 + wr * 64 + i * 16 + g * 4;
#pragma unroll
    for (int j = 0; j < 4; j++) {
      const int col = nb + wc * 64 + j * 16 + lc;
      const float bvv = bias[col];
#pragma unroll
      for (int r = 0; r < 4; r++) {
        float v = (acc[i][j][r] + bvv) * oscale;
        Cb[(long)act[ribase + r] * 1024L + col] = f2bf(v);
      }
    }
  }
}

// ---------------- flash attention, swapped QK^T, 2-tile pipelined PV ----------
__global__ __launch_bounds__(256, 2) void flash_kernel(
    const unsigned short* __restrict__ Q, const unsigned short* __restrict__ Kb,
    const unsigned short* __restrict__ Vt,
    unsigned short* __restrict__ zatt, float* __restrict__ Mo, float* __restrict__ Lo) {
  __shared__ unsigned short lK[2][64 * 128];   // [key][dh], 256B rows (32KB)
  __shared__ unsigned short lV[3][128 * 64];   // [dh][key-slot], 128B rows (48KB)
  const int t = threadIdx.x, wid = t >> 6, lane = t & 63;
  const int g = lane >> 4, lc = lane & 15;
  const int d = blockIdx.x + 16 * (blockIdx.y + 8 * blockIdx.z);
  const int qd = d >> 3, rd = d & 7;
  const int grp = rd + 8 * (qd >> 4);
  const int b = grp >> 3, h = grp & 7, q0 = (qd & 15) * 128;
  const int k_l4 = lane >> 4, k_c = lane & 15;  // K stage: 4 rows/instr
  const int v_l3 = lane >> 3, v_c = lane & 7;   // V stage: 8 rows/instr

  s16x8 qf[2][4];
#pragma unroll
  for (int qi = 0; qi < 2; qi++)
#pragma unroll
    for (int kk = 0; kk < 4; kk++)
      qf[qi][kk] = *(const s16x8*)(Q +
          ((long)(b * S_ + q0 + wid * 32 + qi * 16 + lc)) * D_ + h * DH_ + kk * 32 + g * 8);

  f32x4 acco[2][8];
#pragma unroll
  for (int qi = 0; qi < 2; qi++)
#pragma unroll
    for (int dn = 0; dn < 8; dn++) acco[qi][dn] = (f32x4){0.f, 0.f, 0.f, 0.f};
  float m_run[2] = {-1e30f, -1e30f}, l_run[2] = {0.f, 0.f};
  unsigned wp[2][4][2];  // P(t-1) packed bf16 pairs, persists across barrier

  auto stageK = [&](int kt, int buf) {
#pragma unroll
    for (int i = 0; i < 4; i++) {
      const int r0 = wid * 16 + i * 4;
      const int row = r0 + k_l4;
      gload_lds16((const char*)(Kb + (b * S_ + kt * 64 + row) * D_ + h * DH_) +
                      ((k_c ^ (row & 7)) << 4),
                  (char*)&lK[buf][0] + r0 * 256);
    }
  };
  auto stageV = [&](int kt, int buf) {
#pragma unroll
    for (int i = 0; i < 4; i++) {
      const int r0 = wid * 32 + i * 8;
      const int row = r0 + v_l3;
      gload_lds16((const char*)(Vt + ((b * H_ + h) * DH_ + row) * S_ + kt * 64) +
                      ((v_c ^ (row & 7)) << 4),
                  (char*)&lV[buf][0] + r0 * 128);
    }
  };

  stageK(0, 0);
  stageV(0, 0);
  __syncthreads();

  for (int kt = 0; kt < NT_; ++kt) {
    const int kcur = kt & 1;
    if (kt + 1 < NT_) { stageK(kt + 1, kcur ^ 1); stageV(kt + 1, (kt + 1) % 3); }

    // ---- QK(t) + PV(t-1): two independent MFMA streams, one burst ----
    f32x4 s[2][4];
#pragma unroll
    for (int qi = 0; qi < 2; qi++)
#pragma unroll
      for (int kn = 0; kn < 4; kn++) s[qi][kn] = (f32x4){0.f, 0.f, 0.f, 0.f};
    __builtin_amdgcn_s_setprio(1);
#pragma unroll
    for (int kk = 0; kk < 4; kk++) {
      s16x8 kf[4];
#pragma unroll
      for (int kn = 0; kn < 4; kn++) {
        int row = kn * 16 + lc;
        kf[kn] = *(const s16x8*)((const char*)&lK[kcur][0] + row * 256 +
                                 ((kk * 64 + g * 16) ^ ((row & 7) << 4)));
      }
#pragma unroll
      for (int qi = 0; qi < 2; qi++)
#pragma unroll
        for (int kn = 0; kn < 4; kn++) s[qi][kn] = mfma16(kf[kn], qf[qi][kk], s[qi][kn]);
    }
    if (kt > 0) {  // PV(t-1): reads lV[(kt-1)%3]; stage writes lV[(kt+1)%3] - disjoint
      const int vprev = (kt + 2) % 3;
#pragma unroll
      for (int kk = 0; kk < 2; kk++) {
        s16x8 pf[2];
#pragma unroll
        for (int qi = 0; qi < 2; qi++) {
          union { unsigned u[4]; s16x8 v; } pu;
          pu.u[0] = wp[qi][2 * kk][0];
          pu.u[1] = wp[qi][2 * kk][1];
          pu.u[2] = wp[qi][2 * kk + 1][0];
          pu.u[3] = wp[qi][2 * kk + 1][1];
          pf[qi] = pu.v;
        }
#pragma unroll
        for (int dn = 0; dn < 8; dn++) {
          int vrow = dn * 16 + lc;
          s16x8 vf = *(const s16x8*)((const char*)&lV[vprev][0] + vrow * 128 +
                                     ((kk * 64 + g * 16) ^ ((vrow & 7) << 4)));
#pragma unroll
          for (int qi = 0; qi < 2; qi++) acco[qi][dn] = mfma16(vf, pf[qi], acco[qi][dn]);
        }
      }
    }
    __builtin_amdgcn_s_setprio(0);

    // ---- SM(t): max + defer-rescale (acco now includes PV(t-1)) ----
    float mx[2];
    int trig = 0;
#pragma unroll
    for (int qi = 0; qi < 2; qi++) {
      float m01 = fmaxf(fmaxf(s[qi][0][0], s[qi][0][1]), fmaxf(s[qi][0][2], s[qi][0][3]));
      float m1 = fmaxf(fmaxf(s[qi][1][0], s[qi][1][1]), fmaxf(s[qi][1][2], s[qi][1][3]));
      float m2 = fmaxf(fmaxf(s[qi][2][0], s[qi][2][1]), fmaxf(s[qi][2][2], s[qi][2][3]));
      float m3 = fmaxf(fmaxf(s[qi][3][0], s[qi][3][1]), fmaxf(s[qi][3][2], s[qi][3][3]));
      float m = fmaxf(fmaxf(m01, m1), fmaxf(m2, m3));
      m = fmaxf(m, __shfl_xor(m, 16));
      m = fmaxf(m, __shfl_xor(m, 32));
      mx[qi] = m;
      trig |= (m > m_run[qi] + 8.0f);
    }
    if (__any(trig)) {
#pragma unroll
      for (int qi = 0; qi < 2; qi++) {
        float mn = fmaxf(m_run[qi], mx[qi]);
        float fsc = exp2f(m_run[qi] - mn);
        m_run[qi] = mn;
        l_run[qi] *= fsc;
#pragma unroll
        for (int dn = 0; dn < 8; dn++)
#pragma unroll
          for (int r = 0; r < 4; r++) acco[qi][dn][r] *= fsc;
      }
    }

    // ---- P(t) = exp2(s - m): pack into wp for next-iteration PV ----
#pragma unroll
    for (int qi = 0; qi < 2; qi++) {
      float ls = 0.f;
#pragma unroll
      for (int kn = 0; kn < 4; kn++) {
        float p0 = exp2f(s[qi][kn][0] - m_run[qi]);
        float p1 = exp2f(s[qi][kn][1] - m_run[qi]);
        float p2 = exp2f(s[qi][kn][2] - m_run[qi]);
        float p3 = exp2f(s[qi][kn][3] - m_run[qi]);
        ls += (p0 + p1) + (p2 + p3);
        wp[qi][kn][0] = cvtpk2(p0, p1);
        wp[qi][kn][1] = cvtpk2(p2, p3);
      }
      ls += __shfl_xor(ls, 16);
      ls += __shfl_xor(ls, 32);
      l_run[qi] += ls;
    }
    __syncthreads();  // drains staging; protects lK/lV slot reuse
  }

  // ---- epilogue: PV(NT-1) ----
  {
    const int vprev = (NT_ + 2) % 3;
    __builtin_amdgcn_s_setprio(1);
#pragma unroll
    for (int kk = 0; kk < 2; kk++) {
      s16x8 pf[2];
#pragma unroll
      for (int qi = 0; qi < 2; qi++) {
        union { unsigned u[4]; s16x8 v; } pu;
        pu.u[0] = wp[qi][2 * kk][0];
        pu.u[1] = wp[qi][2 * kk][1];
        pu.u[2] = wp[qi][2 * kk + 1][0];
        pu.u[3] = wp[qi][2 * kk + 1][1];
        pf[qi] = pu.v;
      }
#pragma unroll
      for (int dn = 0; dn < 8; dn++) {
        int vrow = dn * 16 + lc;
        s16x8 vf = *(const s16x8*)((const char*)&lV[vprev][0] + vrow * 128 +
                                   ((kk * 64 + g * 16) ^ ((vrow & 7) << 4)));
#pragma unroll
        for (int qi = 0; qi < 2; qi++) acco[qi][dn] = mfma16(vf, pf[qi], acco[qi][dn]);
      }
    }
    __builtin_amdgcn_s_setprio(0);
  }
  __syncthreads();

  char* tb = (char*)&lK[0][0] + wid * 8192;
#pragma unroll
  for (int qi = 0; qi < 2; qi++) {
    float inv = 1.f / l_run[qi];
    int row = qi * 16 + lc;
#pragma unroll
    for (int dn = 0; dn < 8; dn++) {
      unsigned lo = cvtpk2(acco[qi][dn][0] * inv, acco[qi][dn][1] * inv);
      unsigned hi = cvtpk2(acco[qi][dn][2] * inv, acco[qi][dn][3] * inv);
      unsigned long long pk = (unsigned long long)lo | ((unsigned long long)hi << 32);
      *(unsigned long long*)(tb + row * 256 + ((dn * 32 + g * 8) ^ ((row & 7) << 4))) = pk;
    }
  }
  __syncthreads();
#pragma unroll
  for (int i = 0; i < 8; i++) {
    const int row = i * 4 + (lane >> 4);
    const int chunk = lane & 15;
    s16x8 vv = *(const s16x8*)(tb + row * 256 + ((chunk * 16) ^ ((row & 7) << 4)));
    *(s16x8*)(zatt + ((long)(b * S_ + q0 + wid * 32 + row)) * 2048 + h * DH_ + chunk * 8) = vv;
  }
  if (g == 0) {
#pragma unroll
    for (int qi = 0; qi < 2; qi++) {
      int q = q0 + wid * 32 + qi * 16 + lc;
      Mo[(long)(b * H_ + h) * S_ + q] = m_run[qi];
      Lo[(long)(b * H_ + h) * S_ + q] = l_run[qi];
    }
  }
}

// ---------------- attn_weights = mean over heads (Q prescaled) ----------------
__global__ __launch_bounds__(256) void attw_kernel(
    const unsigned short* __restrict__ Q, const unsigned short* __restrict__ Kb,
    const float* __restrict__ Mo, const float* __restrict__ Lo,
    float* __restrict__ AW) {
  __shared__ unsigned short lK[2][128 * 128];
  __shared__ float lm[H_][128], winv[H_][128];
  const int t = threadIdx.x, wid = t >> 6, lane = t & 63;
  const int g = lane >> 4, lc = lane & 15;
  const int f = blockIdx.x + 16 * (blockIdx.y + 16 * blockIdx.z);
  const int xcd = f & 7, i_ = f >> 3;
  const int grp = (i_ >> 4) * 8 + xcd;
  const int b = grp >> 4, k0 = (grp & 15) * 128, q0 = (i_ & 15) * 128;
  const int k_l4 = lane >> 4, k_c = lane & 15;

  for (int i = t; i < H_ * 128; i += 256) {
    int h = i >> 7, qq = i & 127;
    lm[h][qq] = Mo[(long)(b * H_ + h) * S_ + q0 + qq];
    winv[h][qq] = 0.125f / Lo[(long)(b * H_ + h) * S_ + q0 + qq];
  }

  auto stageK = [&](int h, int buf) {
#pragma unroll
    for (int i = 0; i < 8; i++) {
      const int r0 = wid * 32 + i * 4;
      const int row = r0 + k_l4;
      gload_lds16((const char*)(Kb + ((long)(b * S_ + k0 + row)) * D_ + h * DH_) +
                      ((k_c ^ (row & 7)) << 4),
                  (char*)&lK[buf][0] + r0 * 256);
    }
  };

  f32x4 acc[2][8];
#pragma unroll
  for (int qi = 0; qi < 2; qi++)
#pragma unroll
    for (int kn = 0; kn < 8; kn++) acc[qi][kn] = (f32x4){0.f, 0.f, 0.f, 0.f};

  stageK(0, 0);
  __syncthreads();

  for (int h = 0; h < H_; ++h) {
    const int cur = h & 1;
    if (h + 1 < H_) stageK(h + 1, cur ^ 1);
    f32x4 s[2][8];
#pragma unroll
    for (int qi = 0; qi < 2; qi++)
#pragma unroll
      for (int kn = 0; kn < 8; kn++) s[qi][kn] = (f32x4){0.f, 0.f, 0.f, 0.f};
    __builtin_amdgcn_s_setprio(1);
#pragma unroll
    for (int kk = 0; kk < 4; kk++) {
      s16x8 qa[2];
#pragma unroll
      for (int qi = 0; qi < 2; qi++)
        qa[qi] = *(const s16x8*)(Q +
            ((long)(b * S_ + q0 + wid * 32 + qi * 16 + lc)) * D_ + h * DH_ + kk * 32 + g * 8);
#pragma unroll
      for (int kn = 0; kn < 8; kn++) {
        int row = kn * 16 + lc;
        s16x8 kf = *(const s16x8*)((const char*)&lK[cur][0] + row * 256 +
                                   ((kk * 64 + g * 16) ^ ((row & 7) << 4)));
#pragma unroll
        for (int qi = 0; qi < 2; qi++) s[qi][kn] = mfma16(qa[qi], kf, s[qi][kn]);
      }
    }
    __builtin_amdgcn_s_setprio(0);
#pragma unroll
    for (int qi = 0; qi < 2; qi++)
#pragma unroll
      for (int kn = 0; kn < 8; kn++)
#pragma unroll
        for (int r = 0; r < 4; r++) {
          int qq = wid * 32 + qi * 16 + g * 4 + r;
          acc[qi][kn][r] += exp2f(s[qi][kn][r] - lm[h][qq]) * winv[h][qq];
        }
    __syncthreads();
  }
#pragma unroll
  for (int qi = 0; qi < 2; qi++)
#pragma unroll
    for (int kn = 0; kn < 8; kn++)
#pragma unroll
      for (int r = 0; r < 4; r++) {
        long q = q0 + wid * 32 + qi * 16 + g * 4 + r;
        int k = k0 + kn * 16 + lc;
        AW[((long)b * S_ + q) * S_ + k] = acc[qi][kn][r];
      }
}

__global__ void signal_kernel(float* out, float v) { out[0] = v; }

extern "C" void kernel_launch(void* const* d_in, const int* in_sizes, int n_in,
                              void* d_out, int out_size, void* d_ws, size_t ws_size,
                              hipStream_t stream) {
  constexpr size_t OFF_XB = 0;              // 16 MB
  constexpr size_t OFF_W = 16777216ULL;     // bf16 weights
  constexpr size_t OFF_T = 39845888ULL;     // 16 MB bf16 intermediate (t1)
  constexpr size_t OFF_HR = 56623104ULL;    // 32 MB (wct f32 partials / bf16 hraw)
  constexpr size_t OFF_Z = 90177536ULL;     // 32 MB bf16 [8192,2048]  (hsel | ctx)
  constexpr size_t OFF_Q = 123731968ULL;
  constexpr size_t OFF_K = 140509184ULL;
  constexpr size_t OFF_V = 157286400ULL;
  constexpr size_t OFF_VT = 174063616ULL;
  constexpr size_t OFF_M = 190840832ULL;
  constexpr size_t OFF_L = 191102976ULL;
  constexpr size_t OFF_CNT = 191365120ULL;
  constexpr size_t OFF_RIDX = 191365184ULL;
  constexpr size_t OFF_BC = OFF_RIDX + 2ULL * MTOT * 4;   // bias_c (4KB)
  constexpr size_t OFF_ACT = OFF_BC + 4096;               // active rows
  constexpr size_t OFF_ACT2 = OFF_ACT + MTOT * 4;         // level>=2 rows
  constexpr size_t WS_NEED = OFF_ACT2 + MTOT * 4;

  if (ws_size < WS_NEED) {
    signal_kernel<<<1, 1, 0, stream>>>((float*)d_out, (float)ws_size);
    return;
  }
  const float* x = (const float*)d_in[0];
  const int* levels = (const int*)d_in[1];
  const float* p1w = (const float*)d_in[2];
  const float* p1b = (const float*)d_in[3];
  const float* p2w = (const float*)d_in[4];
  const float* p2b = (const float*)d_in[5];
  const float* lng = (const float*)d_in[6];
  const float* lnb = (const float*)d_in[7];
  const float* wq = (const float*)d_in[8];
  const float* bq = (const float*)d_in[9];
  const float* wk = (const float*)d_in[10];
  const float* bk = (const float*)d_in[11];
  const float* wv = (const float*)d_in[12];
  const float* bv = (const float*)d_in[13];
  const float* wo = (const float*)d_in[14];
  const float* bo = (const float*)d_in[15];
  const float* i1w = (const float*)d_in[16];
  const float* i1b = (const float*)d_in[17];
  const float* i2w = (const float*)d_in[18];
  const float* i2b = (const float*)d_in[19];
  const float* ilng = (const float*)d_in[20];
  const float* ilnb = (const float*)d_in[21];

  char* ws = (char*)d_ws;
  unsigned short* xb = (unsigned short*)(ws + OFF_XB);
  unsigned short* p1t = (unsigned short*)(ws + OFF_W);
  unsigned short* p2t = p1t + 2 * 1048576;
  unsigned short* wqt = p2t + 2 * 1048576;   // [3072][1024] contiguous q|k|v
  unsigned short* wkt = wqt + 1048576;
  unsigned short* wvt = wkt + 1048576;
  unsigned short* wob = wvt + 1048576;       // bf16 wo, NOT transposed
  unsigned short* i1t = wob + 1048576;       // [1024][2048]
  unsigned short* i2t = i1t + 2097152;
  unsigned short* tbuf = (unsigned short*)(ws + OFF_T);  // t1 (silu out)
  float* wctp = (float*)(ws + OFF_HR);                   // [4][1024][1024] f32
  unsigned short* hraw16 = (unsigned short*)(ws + OFF_HR);  // later bf16 [8192][1024]
  unsigned short* z = (unsigned short*)(ws + OFF_Z);  // [8192][2048] hsel|ctx
  unsigned short* qb = (unsigned short*)(ws + OFF_Q);
  unsigned short* kb = (unsigned short*)(ws + OFF_K);
  unsigned short* vb = (unsigned short*)(ws + OFF_V);
  unsigned short* vt = (unsigned short*)(ws + OFF_VT);
  float* Mo = (float*)(ws + OFF_M);
  float* Lo = (float*)(ws + OFF_L);
  int* cnt = (int*)(ws + OFF_CNT);
  int* ridx = (int*)(ws + OFF_RIDX);
  float* bias_c = (float*)(ws + OFF_BC);
  int* act = (int*)(ws + OFF_ACT);
  int* act2 = (int*)(ws + OFF_ACT2);
  float* out = (float*)d_out;
  float* aw = out + (size_t)MTOT * D_;

  dim3 blk(256), blk8(512);
  hipMemsetAsync(cnt, 0, 64, stream);
  hipMemsetAsync(ridx, 0, 2 * MTOT * 4, stream);
  hipMemsetAsync(act, 0, MTOT * 4, stream);
  xconv2_kernel<<<9216, blk, 0, stream>>>(x, xb, wo, wob);
  route_kernel<<<32, blk, 0, stream>>>(levels, cnt, ridx, act, act2);
  lvl2fill_kernel<<<MTOT, blk, 0, stream>>>(act2, cnt + 3, bq, bk, bv, qb, kb, vb, z);

  WtArgs wa;
  wa.d[0] = {p1w, p1t, 1024, 0};
  wa.d[1] = {p1w + 1048576, p1t + 1048576, 1024, 0};
  wa.d[2] = {p2w, p2t, 1024, 0};
  wa.d[3] = {p2w + 1048576, p2t + 1048576, 1024, 0};
  wa.d[4] = {wq, wqt, 1024, 0};
  wa.d[5] = {wk, wkt, 1024, 0};
  wa.d[6] = {wv, wvt, 1024, 0};
  wa.d[7] = {i1w, i1t, 2048, 0};
  wa.d[8] = {i1w + 1048576, i1t, 2048, 1024};
  wa.d[9] = {i2w, i2t, 1024, 0};
  wtrans_all_kernel<<<dim3(32, 320), blk, 0, stream>>>(wa);
  // Wct = W2^T . wo^T, K-split x4 into wctp, then bias_c, then reduce into i1t
  wct_gemm_kernel<<<dim3(8, 32), blk, 0, stream>>>(i1t + 1024, wob, wctp);
  biascomb_kernel<<<1024, blk, 0, stream>>>(i1t, bo, i1b, bias_c);
  wct_reduce_kernel<<<2048, blk, 0, stream>>>(wctp, i1t);

  // merged MoE processor stage (8-wave blocks)
  gemm8_moe_kernel<1><<<dim3(8, 64), blk8, 0, stream>>>(xb, 1024, p1t, 1024, p1b,
                                                        tbuf, 1024, 1024, 1, ridx, cnt);
  gemm8_moe_kernel<0><<<dim3(8, 64), blk8, 0, stream>>>(tbuf, 1024, p2t, 1024, p2b,
                                                        hraw16, 1024, 1024, 0, ridx, cnt);
  ln_moe_kernel<<<8192, blk, 0, stream>>>(hraw16, ridx, cnt, lng, lnb, z, 2048);

  gemm_qkv_kernel<<<dim3(24, 64), blk, 0, stream>>>(z, 2048, wqt, bq, bk, bv, qb, kb, vb,
                                                    act, cnt + 2);
  vtrans_kernel<<<dim3(64, 32, 4), blk, 0, stream>>>(vb, vt);
  flash_kernel<<<dim3(16, 8, 4), blk, 0, stream>>>(qb, kb, vt, z + 1024, Mo, Lo);
  attw_kernel<<<dim3(16, 16, 4), blk, 0, stream>>>(qb, kb, Mo, Lo, aw);
  gemm8_kernel<3><<<dim3(8, 64), blk8, 0, stream>>>(z, 2048, i1t, 2048, bias_c, 1.0f, tbuf,
                                                    1024, 2048, 1);
  gemm8_kernel<4><<<dim3(8, 64), blk8, 0, stream>>>(tbuf, 1024, i2t, 1024, i2b, 1.0f, hraw16,
                                                    1024, 1024, 0);
  ln_kernel<<<8192, blk, 0, stream>>>(hraw16, ilng, ilnb, out);
}

// Round 19
// 427.494 us; speedup vs baseline: 1.2142x; 1.0269x over previous
//
#include <hip/hip_runtime.h>
#include <cstdint>
#include <cstddef>

#define B_ 4
#define S_ 2048
#define D_ 1024
#define H_ 8
#define DH_ 128
#define MTOT 8192
#define NT_ 32
#define SCALE2 (0.08838834764831845f * 1.4426950408889634f)  // 1/sqrt(128) * log2(e)

typedef __attribute__((ext_vector_type(8))) short s16x8;
typedef __attribute__((ext_vector_type(4))) float f32x4;
typedef __attribute__((ext_vector_type(8))) __bf16 bf16x8;

static __device__ __forceinline__ f32x4 mfma16(s16x8 a, s16x8 b, f32x4 c) {
  return __builtin_amdgcn_mfma_f32_16x16x32_bf16(
      __builtin_bit_cast(bf16x8, a), __builtin_bit_cast(bf16x8, b), c, 0, 0, 0);
}
static __device__ __forceinline__ unsigned short f2bf(float f) {
  unsigned u = __builtin_bit_cast(unsigned, f);
  u += 0x7fffu + ((u >> 16) & 1u);
  return (unsigned short)(u >> 16);
}
static __device__ __forceinline__ float bf2f(unsigned short u) {
  return __builtin_bit_cast(float, (unsigned)u << 16);
}
// packed f32x2 -> bf16x2 (lo = a, hi = b)
static __device__ __forceinline__ unsigned cvtpk2(float a, float b) {
  unsigned r;
  asm("v_cvt_pk_bf16_f32 %0, %1, %2" : "=v"(r) : "v"(a), "v"(b));
  return r;
}
// async global->LDS, 16B per lane; LDS dest = wave-uniform base + lane*16
static __device__ __forceinline__ void gload_lds16(const void* g, void* l) {
  __builtin_amdgcn_global_load_lds(
      (__attribute__((address_space(1))) void*)(void*)(g),
      (__attribute__((address_space(3))) void*)(l), 16, 0, 0);
}

// ---------------- x f32 -> bf16 AND wo f32 -> bf16, one launch ----------------
__global__ __launch_bounds__(256) void xconv2_kernel(const float* __restrict__ x,
                                                     unsigned short* __restrict__ xb,
                                                     const float* __restrict__ wo,
                                                     unsigned short* __restrict__ wob) {
  if (blockIdx.x < 8192) {
    long i = ((long)blockIdx.x * 256 + threadIdx.x) * 4;
    float4 v = *(const float4*)(x + i);
    ushort4 o;
    o.x = f2bf(v.x); o.y = f2bf(v.y); o.z = f2bf(v.z); o.w = f2bf(v.w);
    *(ushort4*)(xb + i) = o;
  } else {
    long i = ((long)(blockIdx.x - 8192) * 256 + threadIdx.x) * 4;
    float4 v = *(const float4*)(wo + i);
    ushort4 o;
    o.x = f2bf(v.x); o.y = f2bf(v.y); o.z = f2bf(v.z); o.w = f2bf(v.w);
    *(ushort4*)(wob + i) = o;
  }
}

// ---------------- routing, wave-aggregated (1 atomic per wave per category) ---
__global__ __launch_bounds__(256) void route_kernel(const int* __restrict__ levels,
                                                    int* __restrict__ cnt,
                                                    int* __restrict__ ridx,
                                                    int* __restrict__ act,
                                                    int* __restrict__ act2) {
  const int row = blockIdx.x * 256 + threadIdx.x;
  const int lane = threadIdx.x & 63;
  const int lvl = levels[row];
  const unsigned long long lmlt = (lane == 63) ? ~0ULL >> 1 : (1ULL << lane) - 1;

#pragma unroll
  for (int c = 0; c < 2; c++) {
    bool pred = (lvl == c);
    unsigned long long mask = __ballot(pred);
    int total = __popcll(mask);
    if (total) {
      int leader = __ffsll((long long)mask) - 1;
      int base = 0;
      if (lane == leader) base = atomicAdd(&cnt[c], total);
      base = __shfl(base, leader);
      if (pred) ridx[c * MTOT + base + __popcll(mask & lmlt)] = row;
    }
  }
  {
    bool pred = (lvl < 2);
    unsigned long long mask = __ballot(pred);
    int total = __popcll(mask);
    if (total) {
      int leader = __ffsll((long long)mask) - 1;
      int base = 0;
      if (lane == leader) base = atomicAdd(&cnt[2], total);
      base = __shfl(base, leader);
      if (pred) act[base + __popcll(mask & lmlt)] = row;
    }
    unsigned long long mask2 = ~mask;
    int total2 = 64 - total;
    if (total2) {
      int leader2 = __ffsll((long long)mask2) - 1;
      int base2 = 0;
      if (lane == leader2) base2 = atomicAdd(&cnt[3], total2);
      base2 = __shfl(base2, leader2);
      if (!pred) act2[base2 + __popcll(mask2 & lmlt)] = row;
    }
  }
}

// ---------------- level>=2 rows: q/k/v = bias, hsel half of z = 0 -------------
__global__ __launch_bounds__(256) void lvl2fill_kernel(
    const int* __restrict__ act2, const int* __restrict__ cntp,
    const float* __restrict__ bq, const float* __restrict__ bk,
    const float* __restrict__ bv,
    unsigned short* __restrict__ qb, unsigned short* __restrict__ kb,
    unsigned short* __restrict__ vb, unsigned short* __restrict__ z) {
  const int idx = blockIdx.x;
  if (idx >= *cntp) return;
  const long row = act2[idx];
  const int t = threadIdx.x;
  const float4 q4 = *(const float4*)(bq + t * 4);
  const float4 k4 = *(const float4*)(bk + t * 4);
  const float4 v4 = *(const float4*)(bv + t * 4);
  ushort4 qo, ko, vo;
  qo.x = f2bf(q4.x * SCALE2); qo.y = f2bf(q4.y * SCALE2);
  qo.z = f2bf(q4.z * SCALE2); qo.w = f2bf(q4.w * SCALE2);
  ko.x = f2bf(k4.x); ko.y = f2bf(k4.y); ko.z = f2bf(k4.z); ko.w = f2bf(k4.w);
  vo.x = f2bf(v4.x); vo.y = f2bf(v4.y); vo.z = f2bf(v4.z); vo.w = f2bf(v4.w);
  *(ushort4*)(qb + row * 1024 + t * 4) = qo;
  *(ushort4*)(kb + row * 1024 + t * 4) = ko;
  *(ushort4*)(vb + row * 1024 + t * 4) = vo;
  *(ushort4*)(z + row * 2048 + t * 4) = (ushort4){0, 0, 0, 0};
}

// ---------------- all weight transposes in one launch ----------------
struct WtDesc { const float* src; unsigned short* dst; long dst_ld; long dst_off; };
struct WtArgs { WtDesc d[10]; };
__global__ __launch_bounds__(256) void wtrans_all_kernel(WtArgs a) {
  __shared__ unsigned short tile[32][33];
  const int wi = blockIdx.y >> 5;
  const WtDesc de = a.d[wi];
  int r0 = (blockIdx.y & 31) * 32, c0 = blockIdx.x * 32;
  int tr = threadIdx.x >> 5, tc = threadIdx.x & 31;
#pragma unroll
  for (int i = 0; i < 4; i++)
    tile[tr + i * 8][tc] = f2bf(de.src[(long)(r0 + tr + i * 8) * 1024 + c0 + tc]);
  __syncthreads();
#pragma unroll
  for (int i = 0; i < 4; i++)
    de.dst[(long)(c0 + tr + i * 8) * de.dst_ld + de.dst_off + r0 + tc] = tile[tc][tr + i * 8];
}

// ---------------- v bf16 [B,S,H,DH] -> [B,H,DH,S'] with key-slot permutation --
__global__ __launch_bounds__(256) void vtrans_kernel(const unsigned short* __restrict__ V,
                                                     unsigned short* __restrict__ Vt) {
  __shared__ unsigned short tile[32][33];
  int b = blockIdx.z;
  int h = blockIdx.y >> 2, d0 = (blockIdx.y & 3) * 32;
  int s0 = blockIdx.x * 32;
  int tr = threadIdx.x >> 5, tc = threadIdx.x & 31;
#pragma unroll
  for (int i = 0; i < 4; i++)
    tile[tr + i * 8][tc] = V[((long)(b * S_) + s0 + tr + i * 8) * D_ + h * DH_ + d0 + tc];
  __syncthreads();
  const int sk = s0 + tc;
  const int k6 = sk & 63;
  const int slot = ((k6 >> 5) << 5) | (((k6 >> 2) & 3) << 3) | (((k6 >> 4) & 1) << 2) | (k6 & 3);
  const int ss = (sk & ~63) | slot;
#pragma unroll
  for (int i = 0; i < 4; i++)
    Vt[((long)(b * H_ + h) * DH_ + d0 + tr + i * 8) * S_ + ss] = tile[tc][tr + i * 8];
}

// ---------------- 8-wave GEMM: 128^2 tile, 512 thr ----------------
template <int TAG>
__global__ __launch_bounds__(512) void gemm8_kernel(
    const unsigned short* __restrict__ A, int lda,
    const unsigned short* __restrict__ Wt, int ldw,
    const float* __restrict__ bias, float oscale,
    unsigned short* __restrict__ Cb, int ldc,
    int K, int do_silu) {
  __shared__ unsigned short lA[128 * 64];
  __shared__ unsigned short lB[128 * 64];
  const int t = threadIdx.x;
  const int wid = t >> 6, lane = t & 63;
  const int g = lane >> 4, lc = lane & 15;
  const int wr = wid >> 1, wc = wid & 1;   // 4x2 wave grid: 32-row x 64-col subtiles
  const int nwg = gridDim.x * gridDim.y;
  int flat = blockIdx.x + gridDim.x * blockIdx.y;
  flat = (flat & 7) * (nwg >> 3) + (flat >> 3);
  const int m0 = (flat / gridDim.x) * 128;
  const int n0 = (flat % gridDim.x) * 128;
  const int srow = lane >> 3, scol = lane & 7;
  const int sxor = (scol ^ srow) << 4;

  f32x4 acc[2][4];
#pragma unroll
  for (int i = 0; i < 2; i++)
#pragma unroll
    for (int j = 0; j < 4; j++) acc[i][j] = (f32x4){0.f, 0.f, 0.f, 0.f};

  const int nk = K >> 6;
  for (int kt = 0; kt < nk; ++kt) {
    const int k0 = kt << 6;
#pragma unroll
    for (int i = 0; i < 2; i++) {
      const int r0 = wid * 16 + i * 8;
      gload_lds16((const char*)(A + (m0 + r0 + srow) * (long)lda + k0) + sxor,
                  (char*)lA + r0 * 128);
      gload_lds16((const char*)(Wt + (n0 + r0 + srow) * (long)ldw + k0) + sxor,
                  (char*)lB + r0 * 128);
    }
    __syncthreads();
#pragma unroll
    for (int kk = 0; kk < 2; kk++) {
      s16x8 af[2], bfr[4];
#pragma unroll
      for (int i = 0; i < 2; i++) {
        int row = wr * 32 + i * 16 + lc;
        af[i] = *(const s16x8*)((const char*)lA + row * 128 +
                                ((kk * 64 + g * 16) ^ ((row & 7) << 4)));
      }
#pragma unroll
      for (int j = 0; j < 4; j++) {
        int row = wc * 64 + j * 16 + lc;
        bfr[j] = *(const s16x8*)((const char*)lB + row * 128 +
                                 ((kk * 64 + g * 16) ^ ((row & 7) << 4)));
      }
#pragma unroll
      for (int i = 0; i < 2; i++)
#pragma unroll
        for (int j = 0; j < 4; j++) acc[i][j] = mfma16(af[i], bfr[j], acc[i][j]);
    }
    __syncthreads();
  }
#pragma unroll
  for (int i = 0; i < 2; i++) {
    const long rbase = m0 + wr * 32 + i * 16 + g * 4;
#pragma unroll
    for (int j = 0; j < 4; j++) {
      const int col = n0 + wc * 64 + j * 16 + lc;
      const float bv = bias[col];
#pragma unroll
      for (int r = 0; r < 4; r++) {
        float v = (acc[i][j][r] + bv) * oscale;
        if (do_silu) v = v / (1.f + __expf(-v));
        Cb[(rbase + r) * (long)ldc + col] = f2bf(v);
      }
    }
  }
}

// ---------------- 8-wave merged MoE GEMM ----------------
template <int RMAP>
__global__ __launch_bounds__(512) void gemm8_moe_kernel(
    const unsigned short* __restrict__ A, int lda,
    const unsigned short* __restrict__ Wt0, int ldw,
    const float* __restrict__ bias0,
    unsigned short* __restrict__ Cb, int ldc,
    int K, int do_silu, const int* __restrict__ ridx, const int* __restrict__ cnt2) {
  __shared__ unsigned short lA[128 * 64];
  __shared__ unsigned short lB[128 * 64];
  const int t = threadIdx.x;
  const int wid = t >> 6, lane = t & 63;
  const int g = lane >> 4, lc = lane & 15;
  const int wr = wid >> 1, wc = wid & 1;
  const int nwg = gridDim.x * gridDim.y;
  int flat = blockIdx.x + gridDim.x * blockIdx.y;
  flat = (flat & 7) * (nwg >> 3) + (flat >> 3);
  const int m0 = (flat / gridDim.x) * 128;
  const int n0 = (flat % gridDim.x) * 128;
  const int lvl = m0 >> 12;
  const int lm0 = m0 & 4095;
  if (lm0 >= cnt2[lvl]) return;
  const unsigned short* Wt = Wt0 + (long)lvl * 1048576;
  const float* bias = bias0 + lvl * 1024;
  const int srow = lane >> 3, scol = lane & 7;
  const int sxor = (scol ^ srow) << 4;

  const unsigned short* abase[2];
#pragma unroll
  for (int i = 0; i < 2; i++) {
    int ar;
    if (RMAP) ar = ridx[lvl * MTOT + lm0 + wid * 16 + i * 8 + srow];
    else ar = m0 + wid * 16 + i * 8 + srow;
    abase[i] = A + (long)ar * lda;
  }

  f32x4 acc[2][4];
#pragma unroll
  for (int i = 0; i < 2; i++)
#pragma unroll
    for (int j = 0; j < 4; j++) acc[i][j] = (f32x4){0.f, 0.f, 0.f, 0.f};

  const int nk = K >> 6;
  for (int kt = 0; kt < nk; ++kt) {
    const int k0 = kt << 6;
#pragma unroll
    for (int i = 0; i < 2; i++) {
      const int r0 = wid * 16 + i * 8;
      gload_lds16((const char*)(abase[i] + k0) + sxor, (char*)lA + r0 * 128);
      gload_lds16((const char*)(Wt + (n0 + r0 + srow) * (long)ldw + k0) + sxor,
                  (char*)lB + r0 * 128);
    }
    __syncthreads();
#pragma unroll
    for (int kk = 0; kk < 2; kk++) {
      s16x8 af[2], bfr[4];
#pragma unroll
      for (int i = 0; i < 2; i++) {
        int row = wr * 32 + i * 16 + lc;
        af[i] = *(const s16x8*)((const char*)lA + row * 128 +
                                ((kk * 64 + g * 16) ^ ((row & 7) << 4)));
      }
#pragma unroll
      for (int j = 0; j < 4; j++) {
        int row = wc * 64 + j * 16 + lc;
        bfr[j] = *(const s16x8*)((const char*)lB + row * 128 +
                                 ((kk * 64 + g * 16) ^ ((row & 7) << 4)));
      }
#pragma unroll
      for (int i = 0; i < 2; i++)
#pragma unroll
        for (int j = 0; j < 4; j++) acc[i][j] = mfma16(af[i], bfr[j], acc[i][j]);
    }
    __syncthreads();
  }
#pragma unroll
  for (int i = 0; i < 2; i++) {
    const long rbase = m0 + wr * 32 + i * 16 + g * 4;
#pragma unroll
    for (int j = 0; j < 4; j++) {
      const int col = n0 + wc * 64 + j * 16 + lc;
      const float bv = bias[col];
#pragma unroll
      for (int r = 0; r < 4; r++) {
        float v = acc[i][j][r] + bv;
        if (do_silu) v = v / (1.f + __expf(-v));
        Cb[(rbase + r) * (long)ldc + col] = f2bf(v);
      }
    }
  }
}

// ---------------- Wct partial GEMM ----------------
__global__ __launch_bounds__(256) void wct_gemm_kernel(
    const unsigned short* __restrict__ A,   // i1t+1024, lda 2048
    const unsigned short* __restrict__ Wb,  // wob, ldw 1024
    float* __restrict__ Cf) {               // [4][1024][1024]
  __shared__ unsigned short lA[128 * 64];
  __shared__ unsigned short lB[128 * 64];
  const int t = threadIdx.x;
  const int wid = t >> 6, lane = t & 63;
  const int g = lane >> 4, lc = lane & 15;
  const int wr = wid >> 1, wc = wid & 1;
  const int chunk = blockIdx.y >> 3;
  const int m0 = (blockIdx.y & 7) * 128;
  const int n0 = blockIdx.x * 128;
  const unsigned short* A0 = A + chunk * 256;
  const unsigned short* W0 = Wb + chunk * 256;
  float* C0 = Cf + (long)chunk * 1048576;
  const int srow = lane >> 3, scol = lane & 7;
  const int sxor = (scol ^ srow) << 4;

  f32x4 acc[4][4];
#pragma unroll
  for (int i = 0; i < 4; i++)
#pragma unroll
    for (int j = 0; j < 4; j++) acc[i][j] = (f32x4){0.f, 0.f, 0.f, 0.f};

  for (int kt = 0; kt < 4; ++kt) {
    const int k0 = kt << 6;
#pragma unroll
    for (int i = 0; i < 4; i++) {
      const int r0 = wid * 32 + i * 8;
      gload_lds16((const char*)(A0 + (m0 + r0 + srow) * 2048L + k0) + sxor,
                  (char*)lA + r0 * 128);
      gload_lds16((const char*)(W0 + (n0 + r0 + srow) * 1024L + k0) + sxor,
                  (char*)lB + r0 * 128);
    }
    __syncthreads();
#pragma unroll
    for (int kk = 0; kk < 2; kk++) {
      s16x8 af[4], bfr[4];
#pragma unroll
      for (int i = 0; i < 4; i++) {
        int row = wr * 64 + i * 16 + lc;
        af[i] = *(const s16x8*)((const char*)lA + row * 128 +
                                ((kk * 64 + g * 16) ^ ((row & 7) << 4)));
      }
#pragma unroll
      for (int j = 0; j < 4; j++) {
        int row = wc * 64 + j * 16 + lc;
        bfr[j] = *(const s16x8*)((const char*)lB + row * 128 +
                                 ((kk * 64 + g * 16) ^ ((row & 7) << 4)));
      }
#pragma unroll
      for (int i = 0; i < 4; i++)
#pragma unroll
        for (int j = 0; j < 4; j++) acc[i][j] = mfma16(af[i], bfr[j], acc[i][j]);
    }
    __syncthreads();
  }
#pragma unroll
  for (int i = 0; i < 4; i++) {
    const long rbase = m0 + wr * 64 + i * 16 + g * 4;
#pragma unroll
    for (int j = 0; j < 4; j++) {
      const int col = n0 + wc * 64 + j * 16 + lc;
#pragma unroll
      for (int r = 0; r < 4; r++) C0[(rbase + r) * 1024L + col] = acc[i][j][r];
    }
  }
}

// ---------------- wct reduce: sum 4 K-chunks -> bf16 into i1t cols [1024:2048)
__global__ __launch_bounds__(256) void wct_reduce_kernel(
    const float* __restrict__ hraw, unsigned short* __restrict__ i1t) {
  long e = ((long)blockIdx.x * 256 + threadIdx.x) * 2;
  float a0 = hraw[e] + hraw[e + 1048576] + hraw[e + 2097152] + hraw[e + 3145728];
  float a1 = hraw[e + 1] + hraw[e + 1 + 1048576] + hraw[e + 1 + 2097152] +
             hraw[e + 1 + 3145728];
  unsigned pk = cvtpk2(a0, a1);
  long n = e >> 10, c = e & 1023;
  *(unsigned*)(i1t + n * 2048 + 1024 + c) = pk;
}

// ---------------- bias_c[n] = i1b[n] + sum_a bo[a] * W2t[n,a] (parallel) ------
__global__ __launch_bounds__(256) void biascomb_kernel(
    const unsigned short* __restrict__ i1t, const float* __restrict__ bo,
    const float* __restrict__ i1b, float* __restrict__ bias_c) {
  const int n = blockIdx.x, t = threadIdx.x;
  ushort4 w = *(const ushort4*)(i1t + (long)n * 2048 + 1024 + t * 4);
  float4 b = *(const float4*)(bo + t * 4);
  float s = bf2f(w.x) * b.x + bf2f(w.y) * b.y + bf2f(w.z) * b.z + bf2f(w.w) * b.w;
#pragma unroll
  for (int m = 32; m; m >>= 1) s += __shfl_xor(s, m);
  __shared__ float ws_[4];
  if ((t & 63) == 0) ws_[t >> 6] = s;
  __syncthreads();
  if (t == 0) bias_c[n] = i1b[n] + ws_[0] + ws_[1] + ws_[2] + ws_[3];
}

// ---------------- LayerNorm merged MoE (bf16 in): compact -> scatter ----------
__global__ __launch_bounds__(256) void ln_moe_kernel(
    const unsigned short* __restrict__ in, const int* __restrict__ ridx,
    const int* __restrict__ cnt2,
    const float* __restrict__ gg0, const float* __restrict__ bb0,
    unsigned short* __restrict__ outb, long ldo) {
  const int row = blockIdx.x;
  const int lvl = row >> 12;
  const int lrow = row & 4095;
  if (lrow >= cnt2[lvl]) return;
  const int orow = ridx[lvl * MTOT + lrow];
  const float* gg = gg0 + lvl * 1024;
  const float* bb = bb0 + lvl * 1024;
  const int t = threadIdx.x;
  const ushort4 u = *(const ushort4*)(in + (long)row * D_ + t * 4);
  float v0 = bf2f(u.x), v1 = bf2f(u.y), v2 = bf2f(u.z), v3 = bf2f(u.w);
  float s1 = v0 + v1 + v2 + v3;
  float s2 = v0 * v0 + v1 * v1 + v2 * v2 + v3 * v3;
#pragma unroll
  for (int m = 32; m; m >>= 1) {
    s1 += __shfl_xor(s1, m);
    s2 += __shfl_xor(s2, m);
  }
  __shared__ float w1[4], w2[4];
  if ((t & 63) == 0) { w1[t >> 6] = s1; w2[t >> 6] = s2; }
  __syncthreads();
  s1 = w1[0] + w1[1] + w1[2] + w1[3];
  s2 = w2[0] + w2[1] + w2[2] + w2[3];
  const float mu = s1 * (1.f / D_);
  const float var = s2 * (1.f / D_) - mu * mu;
  const float rs = rsqrtf(var + 1e-5f);
  float vv[4] = {v0, v1, v2, v3};
#pragma unroll
  for (int jj = 0; jj < 4; jj++) {
    int col = t * 4 + jj;
    float y = (vv[jj] - mu) * rs * gg[col] + bb[col];
    outb[(long)orow * ldo + col] = f2bf(y);
  }
}

// ---------------- final LayerNorm (bf16 in, f32 out) ----------------
__global__ __launch_bounds__(256) void ln_kernel(
    const unsigned short* __restrict__ in,
    const float* __restrict__ gg, const float* __restrict__ bb,
    float* __restrict__ outf) {
  const int row = blockIdx.x;
  const int t = threadIdx.x;
  const ushort4 u = *(const ushort4*)(in + (long)row * D_ + t * 4);
  float v0 = bf2f(u.x), v1 = bf2f(u.y), v2 = bf2f(u.z), v3 = bf2f(u.w);
  float s1 = v0 + v1 + v2 + v3;
  float s2 = v0 * v0 + v1 * v1 + v2 * v2 + v3 * v3;
#pragma unroll
  for (int m = 32; m; m >>= 1) {
    s1 += __shfl_xor(s1, m);
    s2 += __shfl_xor(s2, m);
  }
  __shared__ float w1[4], w2[4];
  if ((t & 63) == 0) { w1[t >> 6] = s1; w2[t >> 6] = s2; }
  __syncthreads();
  s1 = w1[0] + w1[1] + w1[2] + w1[3];
  s2 = w2[0] + w2[1] + w2[2] + w2[3];
  const float mu = s1 * (1.f / D_);
  const float var = s2 * (1.f / D_) - mu * mu;
  const float rs = rsqrtf(var + 1e-5f);
  float vv[4] = {v0, v1, v2, v3};
#pragma unroll
  for (int jj = 0; jj < 4; jj++) {
    int col = t * 4 + jj;
    outf[(long)row * D_ + col] = (vv[jj] - mu) * rs * gg[col] + bb[col];
  }
}

// ---------------- fused QKV GEMM, routed over active rows --------------------
__global__ __launch_bounds__(256) void gemm_qkv_kernel(
    const unsigned short* __restrict__ A, int lda,
    const unsigned short* __restrict__ Wt,
    const float* __restrict__ bq, const float* __restrict__ bk,
    const float* __restrict__ bv,
    unsigned short* __restrict__ qb, unsigned short* __restrict__ kb,
    unsigned short* __restrict__ vb,
    const int* __restrict__ act, const int* __restrict__ cntp) {
  __shared__ unsigned short lA[128 * 64];
  __shared__ unsigned short lB[128 * 64];
  const int t = threadIdx.x;
  const int wid = t >> 6, lane = t & 63;
  const int g = lane >> 4, lc = lane & 15;
  const int wr = wid >> 1, wc = wid & 1;
  const int nwg = gridDim.x * gridDim.y;
  int flat = blockIdx.x + gridDim.x * blockIdx.y;
  flat = (flat & 7) * (nwg >> 3) + (flat >> 3);
  const int m0 = (flat / gridDim.x) * 128;
  const int n0 = (flat % gridDim.x) * 128;
  if (m0 >= *cntp) return;
  const int srow = lane >> 3, scol = lane & 7;
  const int sxor = (scol ^ srow) << 4;

  const unsigned short* abase[4];
#pragma unroll
  for (int i = 0; i < 4; i++)
    abase[i] = A + (long)act[m0 + wid * 32 + i * 8 + srow] * lda;

  f32x4 acc[4][4];
#pragma unroll
  for (int i = 0; i < 4; i++)
#pragma unroll
    for (int j = 0; j < 4; j++) acc[i][j] = (f32x4){0.f, 0.f, 0.f, 0.f};

  for (int kt = 0; kt < 16; ++kt) {
    const int k0 = kt << 6;
#pragma unroll
    for (int i = 0; i < 4; i++) {
      const int r0 = wid * 32 + i * 8;
      gload_lds16((const char*)(abase[i] + k0) + sxor, (char*)lA + r0 * 128);
      gload_lds16((const char*)(Wt + (n0 + r0 + srow) * 1024 + k0) + sxor,
                  (char*)lB + r0 * 128);
    }
    __syncthreads();
#pragma unroll
    for (int kk = 0; kk < 2; kk++) {
      s16x8 af[4], bfr[4];
#pragma unroll
      for (int i = 0; i < 4; i++) {
        int row = wr * 64 + i * 16 + lc;
        af[i] = *(const s16x8*)((const char*)lA + row * 128 +
                                ((kk * 64 + g * 16) ^ ((row & 7) << 4)));
      }
#pragma unroll
      for (int j = 0; j < 4; j++) {
        int row = wc * 64 + j * 16 + lc;
        bfr[j] = *(const s16x8*)((const char*)lB + row * 128 +
                                 ((kk * 64 + g * 16) ^ ((row & 7) << 4)));
      }
#pragma unroll
      for (int i = 0; i < 4; i++)
#pragma unroll
        for (int j = 0; j < 4; j++) acc[i][j] = mfma16(af[i], bfr[j], acc[i][j]);
    }
    __syncthreads();
  }
  const int whichB = n0 >> 10;  // block-uniform: 0=q, 1=k, 2=v
  const float* bias = whichB == 0 ? bq : whichB == 1 ? bk : bv;
  unsigned short* Cb = whichB == 0 ? qb : whichB == 1 ? kb : vb;
  const float oscale = whichB == 0 ? (float)SCALE2 : 1.0f;
  const int nb = n0 & 1023;
#pragma unroll
  for (int i = 0; i < 4; i++) {
    const int ribase = m0 + wr * 64 + i * 16 + g * 4;
#pragma unroll
    for (int j = 0; j < 4; j++) {
      const int col = nb + wc * 64 + j * 16 + lc;
      const float bvv = bias[col];
#pragma unroll
      for (int r = 0; r < 4; r++) {
        float v = (acc[i][j][r] + bvv) * oscale;
        Cb[(long)act[ribase + r] * 1024L + col] = f2bf(v);
      }
    }
  }
}

// ---------------- flash attention, swapped QK^T, 2-tile pipelined PV ----------
// l_run kept lane-partial (fsc is group-uniform); cross-lane reduced in epilogue.
__global__ __launch_bounds__(256, 2) void flash_kernel(
    const unsigned short* __restrict__ Q, const unsigned short* __restrict__ Kb,
    const unsigned short* __restrict__ Vt,
    unsigned short* __restrict__ zatt, float* __restrict__ Mo, float* __restrict__ Lo) {
  __shared__ unsigned short lK[2][64 * 128];   // [key][dh], 256B rows (32KB)
  __shared__ unsigned short lV[3][128 * 64];   // [dh][key-slot], 128B rows (48KB)
  const int t = threadIdx.x, wid = t >> 6, lane = t & 63;
  const int g = lane >> 4, lc = lane & 15;
  const int d = blockIdx.x + 16 * (blockIdx.y + 8 * blockIdx.z);
  const int qd = d >> 3, rd = d & 7;
  const int grp = rd + 8 * (qd >> 4);
  const int b = grp >> 3, h = grp & 7, q0 = (qd & 15) * 128;
  const int k_l4 = lane >> 4, k_c = lane & 15;  // K stage: 4 rows/instr
  const int v_l3 = lane >> 3, v_c = lane & 7;   // V stage: 8 rows/instr

  s16x8 qf[2][4];
#pragma unroll
  for (int qi = 0; qi < 2; qi++)
#pragma unroll
    for (int kk = 0; kk < 4; kk++)
      qf[qi][kk] = *(const s16x8*)(Q +
          ((long)(b * S_ + q0 + wid * 32 + qi * 16 + lc)) * D_ + h * DH_ + kk * 32 + g * 8);

  f32x4 acco[2][8];
#pragma unroll
  for (int qi = 0; qi < 2; qi++)
#pragma unroll
    for (int dn = 0; dn < 8; dn++) acco[qi][dn] = (f32x4){0.f, 0.f, 0.f, 0.f};
  float m_run[2] = {-1e30f, -1e30f}, l_run[2] = {0.f, 0.f};
  unsigned wp[2][4][2];  // P(t-1) packed bf16 pairs, persists across barrier

  auto stageK = [&](int kt, int buf) {
#pragma unroll
    for (int i = 0; i < 4; i++) {
      const int r0 = wid * 16 + i * 4;
      const int row = r0 + k_l4;
      gload_lds16((const char*)(Kb + (b * S_ + kt * 64 + row) * D_ + h * DH_) +
                      ((k_c ^ (row & 7)) << 4),
                  (char*)&lK[buf][0] + r0 * 256);
    }
  };
  auto stageV = [&](int kt, int buf) {
#pragma unroll
    for (int i = 0; i < 4; i++) {
      const int r0 = wid * 32 + i * 8;
      const int row = r0 + v_l3;
      gload_lds16((const char*)(Vt + ((b * H_ + h) * DH_ + row) * S_ + kt * 64) +
                      ((v_c ^ (row & 7)) << 4),
                  (char*)&lV[buf][0] + r0 * 128);
    }
  };

  stageK(0, 0);
  stageV(0, 0);
  __syncthreads();

  for (int kt = 0; kt < NT_; ++kt) {
    const int kcur = kt & 1;
    if (kt + 1 < NT_) { stageK(kt + 1, kcur ^ 1); stageV(kt + 1, (kt + 1) % 3); }

    // ---- QK(t) + PV(t-1): two independent MFMA streams, one burst ----
    f32x4 s[2][4];
#pragma unroll
    for (int qi = 0; qi < 2; qi++)
#pragma unroll
      for (int kn = 0; kn < 4; kn++) s[qi][kn] = (f32x4){0.f, 0.f, 0.f, 0.f};
    __builtin_amdgcn_s_setprio(1);
#pragma unroll
    for (int kk = 0; kk < 4; kk++) {
      s16x8 kf[4];
#pragma unroll
      for (int kn = 0; kn < 4; kn++) {
        int row = kn * 16 + lc;
        kf[kn] = *(const s16x8*)((const char*)&lK[kcur][0] + row * 256 +
                                 ((kk * 64 + g * 16) ^ ((row & 7) << 4)));
      }
#pragma unroll
      for (int qi = 0; qi < 2; qi++)
#pragma unroll
        for (int kn = 0; kn < 4; kn++) s[qi][kn] = mfma16(kf[kn], qf[qi][kk], s[qi][kn]);
    }
    if (kt > 0) {  // PV(t-1): reads lV[(kt-1)%3]; stage writes lV[(kt+1)%3] - disjoint
      const int vprev = (kt + 2) % 3;
#pragma unroll
      for (int kk = 0; kk < 2; kk++) {
        s16x8 pf[2];
#pragma unroll
        for (int qi = 0; qi < 2; qi++) {
          union { unsigned u[4]; s16x8 v; } pu;
          pu.u[0] = wp[qi][2 * kk][0];
          pu.u[1] = wp[qi][2 * kk][1];
          pu.u[2] = wp[qi][2 * kk + 1][0];
          pu.u[3] = wp[qi][2 * kk + 1][1];
          pf[qi] = pu.v;
        }
#pragma unroll
        for (int dn = 0; dn < 8; dn++) {
          int vrow = dn * 16 + lc;
          s16x8 vf = *(const s16x8*)((const char*)&lV[vprev][0] + vrow * 128 +
                                     ((kk * 64 + g * 16) ^ ((vrow & 7) << 4)));
#pragma unroll
          for (int qi = 0; qi < 2; qi++) acco[qi][dn] = mfma16(vf, pf[qi], acco[qi][dn]);
        }
      }
    }
    __builtin_amdgcn_s_setprio(0);

    // ---- SM(t): left-chained max (v_max3-friendly) + defer-rescale ----
    float mx[2];
    int trig = 0;
#pragma unroll
    for (int qi = 0; qi < 2; qi++) {
      float m = s[qi][0][0];
#pragma unroll
      for (int kn = 0; kn < 4; kn++)
#pragma unroll
        for (int r = 0; r < 4; r++)
          if (kn || r) m = fmaxf(m, s[qi][kn][r]);
      m = fmaxf(m, __shfl_xor(m, 16));
      m = fmaxf(m, __shfl_xor(m, 32));
      mx[qi] = m;
      trig |= (m > m_run[qi] + 8.0f);
    }
    if (__any(trig)) {
#pragma unroll
      for (int qi = 0; qi < 2; qi++) {
        float mn = fmaxf(m_run[qi], mx[qi]);
        float fsc = exp2f(m_run[qi] - mn);  // group-uniform (m reduced over group)
        m_run[qi] = mn;
        l_run[qi] *= fsc;
#pragma unroll
        for (int dn = 0; dn < 8; dn++)
#pragma unroll
          for (int r = 0; r < 4; r++) acco[qi][dn][r] *= fsc;
      }
    }

    // ---- P(t) = exp2(s - m): pack into wp; l stays lane-partial ----
#pragma unroll
    for (int qi = 0; qi < 2; qi++) {
      float ls = 0.f;
#pragma unroll
      for (int kn = 0; kn < 4; kn++) {
        float p0 = exp2f(s[qi][kn][0] - m_run[qi]);
        float p1 = exp2f(s[qi][kn][1] - m_run[qi]);
        float p2 = exp2f(s[qi][kn][2] - m_run[qi]);
        float p3 = exp2f(s[qi][kn][3] - m_run[qi]);
        ls += (p0 + p1) + (p2 + p3);
        wp[qi][kn][0] = cvtpk2(p0, p1);
        wp[qi][kn][1] = cvtpk2(p2, p3);
      }
      l_run[qi] += ls;  // cross-lane reduce deferred to epilogue
    }
    __syncthreads();  // drains staging; protects lK/lV slot reuse
  }

  // ---- epilogue: PV(NT-1) ----
  {
    const int vprev = (NT_ + 2) % 3;
    __builtin_amdgcn_s_setprio(1);
#pragma unroll
    for (int kk = 0; kk < 2; kk++) {
      s16x8 pf[2];
#pragma unroll
      for (int qi = 0; qi < 2; qi++) {
        union { unsigned u[4]; s16x8 v; } pu;
        pu.u[0] = wp[qi][2 * kk][0];
        pu.u[1] = wp[qi][2 * kk][1];
        pu.u[2] = wp[qi][2 * kk + 1][0];
        pu.u[3] = wp[qi][2 * kk + 1][1];
        pf[qi] = pu.v;
      }
#pragma unroll
      for (int dn = 0; dn < 8; dn++) {
        int vrow = dn * 16 + lc;
        s16x8 vf = *(const s16x8*)((const char*)&lV[vprev][0] + vrow * 128 +
                                   ((kk * 64 + g * 16) ^ ((vrow & 7) << 4)));
#pragma unroll
        for (int qi = 0; qi < 2; qi++) acco[qi][dn] = mfma16(vf, pf[qi], acco[qi][dn]);
      }
    }
    __builtin_amdgcn_s_setprio(0);
  }
  // deferred cross-lane l reduction (group-uniform result)
#pragma unroll
  for (int qi = 0; qi < 2; qi++) {
    l_run[qi] += __shfl_xor(l_run[qi], 16);
    l_run[qi] += __shfl_xor(l_run[qi], 32);
  }
  __syncthreads();

  char* tb = (char*)&lK[0][0] + wid * 8192;
#pragma unroll
  for (int qi = 0; qi < 2; qi++) {
    float inv = 1.f / l_run[qi];
    int row = qi * 16 + lc;
#pragma unroll
    for (int dn = 0; dn < 8; dn++) {
      unsigned lo = cvtpk2(acco[qi][dn][0] * inv, acco[qi][dn][1] * inv);
      unsigned hi = cvtpk2(acco[qi][dn][2] * inv, acco[qi][dn][3] * inv);
      unsigned long long pk = (unsigned long long)lo | ((unsigned long long)hi << 32);
      *(unsigned long long*)(tb + row * 256 + ((dn * 32 + g * 8) ^ ((row & 7) << 4))) = pk;
    }
  }
  __syncthreads();
#pragma unroll
  for (int i = 0; i < 8; i++) {
    const int row = i * 4 + (lane >> 4);
    const int chunk = lane & 15;
    s16x8 vv = *(const s16x8*)(tb + row * 256 + ((chunk * 16) ^ ((row & 7) << 4)));
    *(s16x8*)(zatt + ((long)(b * S_ + q0 + wid * 32 + row)) * 2048 + h * DH_ + chunk * 8) = vv;
  }
  if (g == 0) {
#pragma unroll
    for (int qi = 0; qi < 2; qi++) {
      int q = q0 + wid * 32 + qi * 16 + lc;
      Mo[(long)(b * H_ + h) * S_ + q] = m_run[qi];
      Lo[(long)(b * H_ + h) * S_ + q] = l_run[qi];
    }
  }
}

// ---------------- attn_weights = mean over heads (Q prescaled) ----------------
__global__ __launch_bounds__(256) void attw_kernel(
    const unsigned short* __restrict__ Q, const unsigned short* __restrict__ Kb,
    const float* __restrict__ Mo, const float* __restrict__ Lo,
    float* __restrict__ AW) {
  __shared__ unsigned short lK[2][128 * 128];
  __shared__ float lm[H_][128], winv[H_][128];
  const int t = threadIdx.x, wid = t >> 6, lane = t & 63;
  const int g = lane >> 4, lc = lane & 15;
  const int f = blockIdx.x + 16 * (blockIdx.y + 16 * blockIdx.z);
  const int xcd = f & 7, i_ = f >> 3;
  const int grp = (i_ >> 4) * 8 + xcd;
  const int b = grp >> 4, k0 = (grp & 15) * 128, q0 = (i_ & 15) * 128;
  const int k_l4 = lane >> 4, k_c = lane & 15;

  for (int i = t; i < H_ * 128; i += 256) {
    int h = i >> 7, qq = i & 127;
    lm[h][qq] = Mo[(long)(b * H_ + h) * S_ + q0 + qq];
    winv[h][qq] = 0.125f / Lo[(long)(b * H_ + h) * S_ + q0 + qq];
  }

  auto stageK = [&](int h, int buf) {
#pragma unroll
    for (int i = 0; i < 8; i++) {
      const int r0 = wid * 32 + i * 4;
      const int row = r0 + k_l4;
      gload_lds16((const char*)(Kb + ((long)(b * S_ + k0 + row)) * D_ + h * DH_) +
                      ((k_c ^ (row & 7)) << 4),
                  (char*)&lK[buf][0] + r0 * 256);
    }
  };

  f32x4 acc[2][8];
#pragma unroll
  for (int qi = 0; qi < 2; qi++)
#pragma unroll
    for (int kn = 0; kn < 8; kn++) acc[qi][kn] = (f32x4){0.f, 0.f, 0.f, 0.f};

  stageK(0, 0);
  __syncthreads();

  for (int h = 0; h < H_; ++h) {
    const int cur = h & 1;
    if (h + 1 < H_) stageK(h + 1, cur ^ 1);
    f32x4 s[2][8];
#pragma unroll
    for (int qi = 0; qi < 2; qi++)
#pragma unroll
      for (int kn = 0; kn < 8; kn++) s[qi][kn] = (f32x4){0.f, 0.f, 0.f, 0.f};
    __builtin_amdgcn_s_setprio(1);
#pragma unroll
    for (int kk = 0; kk < 4; kk++) {
      s16x8 qa[2];
#pragma unroll
      for (int qi = 0; qi < 2; qi++)
        qa[qi] = *(const s16x8*)(Q +
            ((long)(b * S_ + q0 + wid * 32 + qi * 16 + lc)) * D_ + h * DH_ + kk * 32 + g * 8);
#pragma unroll
      for (int kn = 0; kn < 8; kn++) {
        int row = kn * 16 + lc;
        s16x8 kf = *(const s16x8*)((const char*)&lK[cur][0] + row * 256 +
                                   ((kk * 64 + g * 16) ^ ((row & 7) << 4)));
#pragma unroll
        for (int qi = 0; qi < 2; qi++) s[qi][kn] = mfma16(qa[qi], kf, s[qi][kn]);
      }
    }
    __builtin_amdgcn_s_setprio(0);
#pragma unroll
    for (int qi = 0; qi < 2; qi++)
#pragma unroll
      for (int kn = 0; kn < 8; kn++)
#pragma unroll
        for (int r = 0; r < 4; r++) {
          int qq = wid * 32 + qi * 16 + g * 4 + r;
          acc[qi][kn][r] += exp2f(s[qi][kn][r] - lm[h][qq]) * winv[h][qq];
        }
    __syncthreads();
  }
#pragma unroll
  for (int qi = 0; qi < 2; qi++)
#pragma unroll
    for (int kn = 0; kn < 8; kn++)
#pragma unroll
      for (int r = 0; r < 4; r++) {
        long q = q0 + wid * 32 + qi * 16 + g * 4 + r;
        int k = k0 + kn * 16 + lc;
        AW[((long)b * S_ + q) * S_ + k] = acc[qi][kn][r];
      }
}

__global__ void signal_kernel(float* out, float v) { out[0] = v; }

extern "C" void kernel_launch(void* const* d_in, const int* in_sizes, int n_in,
                              void* d_out, int out_size, void* d_ws, size_t ws_size,
                              hipStream_t stream) {
  constexpr size_t OFF_XB = 0;              // 16 MB
  constexpr size_t OFF_W = 16777216ULL;     // bf16 weights
  constexpr size_t OFF_T = 39845888ULL;     // 16 MB bf16 intermediate (t1)
  constexpr size_t OFF_HR = 56623104ULL;    // 32 MB (wct f32 partials / bf16 hraw)
  constexpr size_t OFF_Z = 90177536ULL;     // 32 MB bf16 [8192,2048]  (hsel | ctx)
  constexpr size_t OFF_Q = 123731968ULL;
  constexpr size_t OFF_K = 140509184ULL;
  constexpr size_t OFF_V = 157286400ULL;
  constexpr size_t OFF_VT = 174063616ULL;
  constexpr size_t OFF_M = 190840832ULL;
  constexpr size_t OFF_L = 191102976ULL;
  constexpr size_t OFF_CNT = 191365120ULL;
  constexpr size_t OFF_RIDX = 191365184ULL;
  constexpr size_t OFF_BC = OFF_RIDX + 2ULL * MTOT * 4;   // bias_c (4KB)
  constexpr size_t OFF_ACT = OFF_BC + 4096;               // active rows
  constexpr size_t OFF_ACT2 = OFF_ACT + MTOT * 4;         // level>=2 rows
  constexpr size_t WS_NEED = OFF_ACT2 + MTOT * 4;

  if (ws_size < WS_NEED) {
    signal_kernel<<<1, 1, 0, stream>>>((float*)d_out, (float)ws_size);
    return;
  }
  const float* x = (const float*)d_in[0];
  const int* levels = (const int*)d_in[1];
  const float* p1w = (const float*)d_in[2];
  const float* p1b = (const float*)d_in[3];
  const float* p2w = (const float*)d_in[4];
  const float* p2b = (const float*)d_in[5];
  const float* lng = (const float*)d_in[6];
  const float* lnb = (const float*)d_in[7];
  const float* wq = (const float*)d_in[8];
  const float* bq = (const float*)d_in[9];
  const float* wk = (const float*)d_in[10];
  const float* bk = (const float*)d_in[11];
  const float* wv = (const float*)d_in[12];
  const float* bv = (const float*)d_in[13];
  const float* wo = (const float*)d_in[14];
  const float* bo = (const float*)d_in[15];
  const float* i1w = (const float*)d_in[16];
  const float* i1b = (const float*)d_in[17];
  const float* i2w = (const float*)d_in[18];
  const float* i2b = (const float*)d_in[19];
  const float* ilng = (const float*)d_in[20];
  const float* ilnb = (const float*)d_in[21];

  char* ws = (char*)d_ws;
  unsigned short* xb = (unsigned short*)(ws + OFF_XB);
  unsigned short* p1t = (unsigned short*)(ws + OFF_W);
  unsigned short* p2t = p1t + 2 * 1048576;
  unsigned short* wqt = p2t + 2 * 1048576;   // [3072][1024] contiguous q|k|v
  unsigned short* wkt = wqt + 1048576;
  unsigned short* wvt = wkt + 1048576;
  unsigned short* wob = wvt + 1048576;       // bf16 wo, NOT transposed
  unsigned short* i1t = wob + 1048576;       // [1024][2048]
  unsigned short* i2t = i1t + 2097152;
  unsigned short* tbuf = (unsigned short*)(ws + OFF_T);  // t1 (silu out)
  float* wctp = (float*)(ws + OFF_HR);                   // [4][1024][1024] f32
  unsigned short* hraw16 = (unsigned short*)(ws + OFF_HR);  // later bf16 [8192][1024]
  unsigned short* z = (unsigned short*)(ws + OFF_Z);  // [8192][2048] hsel|ctx
  unsigned short* qb = (unsigned short*)(ws + OFF_Q);
  unsigned short* kb = (unsigned short*)(ws + OFF_K);
  unsigned short* vb = (unsigned short*)(ws + OFF_V);
  unsigned short* vt = (unsigned short*)(ws + OFF_VT);
  float* Mo = (float*)(ws + OFF_M);
  float* Lo = (float*)(ws + OFF_L);
  int* cnt = (int*)(ws + OFF_CNT);
  int* ridx = (int*)(ws + OFF_RIDX);
  float* bias_c = (float*)(ws + OFF_BC);
  int* act = (int*)(ws + OFF_ACT);
  int* act2 = (int*)(ws + OFF_ACT2);
  float* out = (float*)d_out;
  float* aw = out + (size_t)MTOT * D_;

  dim3 blk(256), blk8(512);
  hipMemsetAsync(cnt, 0, 64, stream);
  hipMemsetAsync(ridx, 0, 2 * MTOT * 4, stream);
  hipMemsetAsync(act, 0, MTOT * 4, stream);
  xconv2_kernel<<<9216, blk, 0, stream>>>(x, xb, wo, wob);
  route_kernel<<<32, blk, 0, stream>>>(levels, cnt, ridx, act, act2);
  lvl2fill_kernel<<<MTOT, blk, 0, stream>>>(act2, cnt + 3, bq, bk, bv, qb, kb, vb, z);

  WtArgs wa;
  wa.d[0] = {p1w, p1t, 1024, 0};
  wa.d[1] = {p1w + 1048576, p1t + 1048576, 1024, 0};
  wa.d[2] = {p2w, p2t, 1024, 0};
  wa.d[3] = {p2w + 1048576, p2t + 1048576, 1024, 0};
  wa.d[4] = {wq, wqt, 1024, 0};
  wa.d[5] = {wk, wkt, 1024, 0};
  wa.d[6] = {wv, wvt, 1024, 0};
  wa.d[7] = {i1w, i1t, 2048, 0};
  wa.d[8] = {i1w + 1048576, i1t, 2048, 1024};
  wa.d[9] = {i2w, i2t, 1024, 0};
  wtrans_all_kernel<<<dim3(32, 320), blk, 0, stream>>>(wa);
  // Wct = W2^T . wo^T, K-split x4 into wctp, then bias_c, then reduce into i1t
  wct_gemm_kernel<<<dim3(8, 32), blk, 0, stream>>>(i1t + 1024, wob, wctp);
  biascomb_kernel<<<1024, blk, 0, stream>>>(i1t, bo, i1b, bias_c);
  wct_reduce_kernel<<<2048, blk, 0, stream>>>(wctp, i1t);

  // merged MoE processor stage (8-wave blocks)
  gemm8_moe_kernel<1><<<dim3(8, 64), blk8, 0, stream>>>(xb, 1024, p1t, 1024, p1b,
                                                        tbuf, 1024, 1024, 1, ridx, cnt);
  gemm8_moe_kernel<0><<<dim3(8, 64), blk8, 0, stream>>>(tbuf, 1024, p2t, 1024, p2b,
                                                        hraw16, 1024, 1024, 0, ridx, cnt);
  ln_moe_kernel<<<8192, blk, 0, stream>>>(hraw16, ridx, cnt, lng, lnb, z, 2048);

  gemm_qkv_kernel<<<dim3(24, 64), blk, 0, stream>>>(z, 2048, wqt, bq, bk, bv, qb, kb, vb,
                                                    act, cnt + 2);
  vtrans_kernel<<<dim3(64, 32, 4), blk, 0, stream>>>(vb, vt);
  flash_kernel<<<dim3(16, 8, 4), blk, 0, stream>>>(qb, kb, vt, z + 1024, Mo, Lo);
  attw_kernel<<<dim3(16, 16, 4), blk, 0, stream>>>(qb, kb, Mo, Lo, aw);
  gemm8_kernel<3><<<dim3(8, 64), blk8, 0, stream>>>(z, 2048, i1t, 2048, bias_c, 1.0f, tbuf,
                                                    1024, 2048, 1);
  gemm8_kernel<4><<<dim3(8, 64), blk8, 0, stream>>>(tbuf, 1024, i2t, 1024, i2b, 1.0f, hraw16,
                                                    1024, 1024, 0);
  ln_kernel<<<8192, blk, 0, stream>>>(hraw16, ilng, ilnb, out);
}